// Round 9
// baseline (387.693 us; speedup 1.0000x reference)
//
#include <hip/hip_runtime.h>
#include <hip/hip_bf16.h>
#include <math.h>

// MoE: 8 experts, top-2, H=1024, I=4096, T=2048. f32 in/out, bf16 MFMA inside.
// Round 9: expert-staged pipeline — D0: tconv13(e0-3); D1: g1(e0-3) || tconv13(e4-7);
// D2: g1(e4-7) || w2 transpose; D3: g2; D4: combine. All inner loops identical to
// r8 (verified), factored into device functions shared by all paths.
constexpr int kNE = 8;
constexpr int kH  = 1024;
constexpr int kI  = 4096;
constexpr int kT  = 2048;
constexpr int kMaxSlots = kT * 2 + kNE * 64;   // 4608
constexpr int kSlotPad  = kMaxSlots + 128;

typedef short bf16x8 __attribute__((ext_vector_type(8)));
typedef float f32x4  __attribute__((ext_vector_type(4)));

__device__ __forceinline__ short f2bf(float f) {
  union { float f; unsigned u; } v; v.f = f;
  unsigned r = v.u + 0x7fffu + ((v.u >> 16) & 1u);   // RNE
  return (short)(r >> 16);
}

__device__ __forceinline__ void gload16(const void* g, void* lds) {
  __builtin_amdgcn_global_load_lds(
      (const __attribute__((address_space(1))) void*)g,
      (__attribute__((address_space(3))) void*)lds, 16, 0, 0);
}

// ================= shared device building blocks ============================

// w1/w3 transpose tile (128k x 128n, 64KB LDS), counted-vmcnt pipeline.
// dst: packed w13t [E][8192][1024].
__device__ __forceinline__ void tconv13_tile(
    char* smemraw, int e, int sel, int tile,
    const float* __restrict__ w1s, const float* __restrict__ w3s,
    short* __restrict__ w13t) {
  float* lds = (float*)smemraw;
  const float* src = (sel ? w3s : w1s) + (size_t)e * kH * kI;
  const int nb = (tile & 31) * 128;
  const int kb = (tile >> 5) * 128;
  const int tid = threadIdx.x;
#pragma unroll
  for (int p = 0; p < 16; ++p) {
    const int q = p * 256 + tid;
    const int k = q >> 5;
    const int nc = (q & 31) * 4;
    gload16(src + (size_t)(kb + k) * kI + nb + nc, (char*)lds + (size_t)q * 16);
  }
  const int c = tid & 127;
  const int kh2 = tid >> 7;
  const int n = nb + c;
  const size_t drow = (size_t)e * 8192 + ((n >> 5) * 64 + sel * 32 + (n & 31));
  short* dbase = w13t + drow * kH + kb;
#define CONV_SUB(S, WAITSTR)                                                  \
  do {                                                                        \
    asm volatile(WAITSTR ::: "memory");                                       \
    __builtin_amdgcn_s_barrier();                                             \
    __builtin_amdgcn_sched_barrier(0);                                        \
    _Pragma("unroll")                                                         \
    for (int i = 0; i < 2; ++i) {                                             \
      const int kc = (S) * 4 + kh2 * 2 + i;                                   \
      bf16x8 v;                                                               \
      _Pragma("unroll")                                                       \
      for (int j = 0; j < 8; ++j) v[j] = f2bf(lds[(kc * 8 + j) * 128 + c]);   \
      *(bf16x8*)(dbase + kc * 8) = v;                                         \
    }                                                                         \
  } while (0)
  CONV_SUB(0, "s_waitcnt vmcnt(12)");
  CONV_SUB(1, "s_waitcnt vmcnt(8)");
  CONV_SUB(2, "s_waitcnt vmcnt(4)");
  CONV_SUB(3, "s_waitcnt vmcnt(0)");
#undef CONV_SUB
}

// w2 transpose pair (two 128k x 64n tiles, 32KB LDS). dst: w2t [E][1024][4096].
__device__ __forceinline__ void w2t_pair(
    char* smemraw, int bt, const float* __restrict__ w2s,
    short* __restrict__ w2t) {
  float* tile = (float*)smemraw;
  const int tid = threadIdx.x;
#pragma unroll 1
  for (int s = 0; s < 2; ++s) {
    const int t = bt * 2 + s;                       // 0..4095
    const int e2 = t >> 9;
    const int r = t & 511;
    const int kbT = (r >> 4) * 128;
    const int nbT = (r & 15) * 64;
    const float* src = w2s + ((size_t)e2 * kI + kbT) * kH + nbT;
    if (s) __syncthreads();                         // LDS reuse WAR
#pragma unroll
    for (int p = 0; p < 8; ++p) {
      const int q = p * 256 + tid;
      const int k = q >> 4;
      const int nc = (q & 15) * 4;
      gload16(src + (size_t)k * kH + nc, (char*)tile + q * 16);
    }
    __syncthreads();                                // drains vmcnt
    const int c = tid & 63;
    const int kw = tid >> 6;
    short* drow = w2t + ((size_t)e2 * kH + nbT + c) * kI + kbT;
#pragma unroll
    for (int i = 0; i < 4; ++i) {
      const int kc = kw * 4 + i;
      bf16x8 v;
#pragma unroll
      for (int j = 0; j < 8; ++j) v[j] = f2bf(tile[(kc * 8 + j) * 64 + c]);
      *(bf16x8*)(drow + kc * 8) = v;
    }
  }
}

// GEMM1 block: 128m x 128pc, 4 waves, BK=64, 32KB LDS (r5-r8 verified loop).
__device__ __forceinline__ void g1_gemm_block(
    char* smem, int e, int rb, int nb,
    const short* __restrict__ hsb, const short* __restrict__ w13t,
    const int* __restrict__ cnt, const int* __restrict__ off,
    const int* __restrict__ slot_token, short* __restrict__ inter) {
  const int count = cnt[e];
  if (rb * 128 >= count) return;
  const int slot0 = off[e] + rb * 128;
  const int mlim = ((count + 63) & ~63) - rb * 128;

  short* As = (short*)smem;                         // 16KB [row][slot]
  short* Bs = (short*)(smem + 16384);               // 16KB
  const int tid = threadIdx.x;
  const int l = tid & 63, w = tid >> 6;
  const int wr = w >> 1, wc = w & 1;

  const int srow = l >> 3;
  const int sch  = (l & 7) ^ srow;
  const short* aptr[4];
  const short* bptr[4];
  unsigned sdst[4];
#pragma unroll
  for (int i = 0; i < 4; ++i) {
    const int q = w * 4 + i;
    const int row = q * 8 + srow;
    int tok = slot_token[slot0 + row]; if (tok < 0) tok = 0;
    aptr[i] = hsb + (size_t)tok * kH + sch * 8;
    bptr[i] = w13t + ((size_t)e * 8192 + nb * 128 + row) * kH + sch * 8;
    sdst[i] = (unsigned)(q * 1024 + l * 16);
  }

  f32x4 acc[4][4];
#pragma unroll
  for (int mi = 0; mi < 4; ++mi)
#pragma unroll
    for (int ni = 0; ni < 4; ++ni)
#pragma unroll
      for (int r = 0; r < 4; ++r) acc[mi][ni][r] = 0.f;

  const int r16 = l & 15, g = l >> 4;

  for (int t = 0; t < kH / 64; ++t) {
    const int k0 = t * 64;
#pragma unroll
    for (int i = 0; i < 4; ++i) {
      gload16(aptr[i] + k0, (char*)As + sdst[i]);
      gload16(bptr[i] + k0, (char*)Bs + sdst[i]);
    }
    __syncthreads();
#pragma unroll
    for (int kk = 0; kk < 2; ++kk) {
      const int chunk = kk * 4 + g;
      bf16x8 af[4], bf[4];
#pragma unroll
      for (int mi = 0; mi < 4; ++mi) {
        const int m = wr * 64 + mi * 16 + r16;
        af[mi] = *(const bf16x8*)((const char*)As + m * 128 + ((chunk ^ (m & 7)) * 16));
      }
#pragma unroll
      for (int ni = 0; ni < 4; ++ni) {
        const int n = wc * 64 + ni * 16 + r16;
        bf[ni] = *(const bf16x8*)((const char*)Bs + n * 128 + ((chunk ^ (n & 7)) * 16));
      }
#pragma unroll
      for (int mi = 0; mi < 4; ++mi)
#pragma unroll
        for (int ni = 0; ni < 4; ++ni)
          acc[mi][ni] = __builtin_amdgcn_mfma_f32_16x16x32_bf16(
              af[mi], bf[ni], acc[mi][ni], 0, 0, 0);
    }
    __syncthreads();
  }

  const int colb = (nb * 2 + wc) * 32;
#pragma unroll
  for (int mi = 0; mi < 4; ++mi)
#pragma unroll
    for (int r = 0; r < 4; ++r) {
      const int m = wr * 64 + mi * 16 + g * 4 + r;
      if (m < mlim) {
#pragma unroll
        for (int ni = 0; ni < 2; ++ni) {
          float h1 = acc[mi][ni][r];
          float h3 = acc[mi][ni + 2][r];
          float y = h1 / (1.f + expf(-h1)) * h3;
          inter[(size_t)(slot0 + m) * kI + colb + ni * 16 + r16] = f2bf(y);
        }
      }
    }
}

// ========================= small kernels ====================================

__global__ __launch_bounds__(256) void router_convhs_kernel(
    const float* __restrict__ hs, const float* __restrict__ gw,
    int* __restrict__ cnt, int* __restrict__ tok_e, float* __restrict__ tok_w,
    short* __restrict__ hsb) {
  if (blockIdx.x >= kT / 4) {
    const int idx = (blockIdx.x - kT / 4) * 256 + threadIdx.x;
    const float* p = hs + (size_t)idx * 8;
    float4 a = *(const float4*)p;
    float4 b = *(const float4*)(p + 4);
    bf16x8 w;
    w[0] = f2bf(a.x); w[1] = f2bf(a.y); w[2] = f2bf(a.z); w[3] = f2bf(a.w);
    w[4] = f2bf(b.x); w[5] = f2bf(b.y); w[6] = f2bf(b.z); w[7] = f2bf(b.w);
    *(bf16x8*)(hsb + (size_t)idx * 8) = w;
    return;
  }
  const int lane = threadIdx.x & 63;
  const int wid  = threadIdx.x >> 6;
  const int t = blockIdx.x * 4 + wid;
  const float* hrow = hs + (size_t)t * kH;
  float acc[kNE];
#pragma unroll
  for (int e = 0; e < kNE; ++e) acc[e] = 0.f;
  for (int i = lane; i < kH; i += 64) {
    float x = hrow[i];
    float4 g0 = *(const float4*)(gw + (size_t)i * kNE);
    float4 g1 = *(const float4*)(gw + (size_t)i * kNE + 4);
    acc[0] += x * g0.x; acc[1] += x * g0.y; acc[2] += x * g0.z; acc[3] += x * g0.w;
    acc[4] += x * g1.x; acc[5] += x * g1.y; acc[6] += x * g1.z; acc[7] += x * g1.w;
  }
#pragma unroll
  for (int o = 32; o; o >>= 1)
#pragma unroll
    for (int e = 0; e < kNE; ++e) acc[e] += __shfl_xor(acc[e], o);
  if (lane == 0) {
    int e0 = 0;
#pragma unroll
    for (int e = 1; e < kNE; ++e) if (acc[e] > acc[e0]) e0 = e;
    int e1 = (e0 == 0) ? 1 : 0;
#pragma unroll
    for (int e = 0; e < kNE; ++e) if (e != e0 && acc[e] > acc[e1]) e1 = e;
    float d  = acc[e1] - acc[e0];
    float w0 = 1.f / (1.f + expf(d));
    float w1 = 1.f / (1.f + expf(-d));
    atomicAdd(&cnt[e0], 1);
    atomicAdd(&cnt[e1], 1);
    tok_e[t * 2] = e0; tok_e[t * 2 + 1] = e1;
    tok_w[t * 2] = w0; tok_w[t * 2 + 1] = w1;
  }
}

__global__ __launch_bounds__(256) void offsets_kernel(
    const int* __restrict__ cnt, int* __restrict__ off,
    int* __restrict__ slot_token, float* __restrict__ slot_weight) {
  if (threadIdx.x == 0) {
    int o = 0;
#pragma unroll
    for (int e = 0; e < kNE; ++e) { off[e] = o; o += (cnt[e] + 63) & ~63; }
    off[kNE] = o;
  }
  for (int i = threadIdx.x; i < kSlotPad; i += 256) {
    slot_token[i]  = -1;
    slot_weight[i] = 0.f;
  }
}

__global__ __launch_bounds__(256) void assign_kernel(
    const int* __restrict__ tok_e, const float* __restrict__ tok_w,
    const int* __restrict__ off, int* __restrict__ cursor,
    int* __restrict__ slot_token, float* __restrict__ slot_weight,
    int* __restrict__ token_slots) {
  const int t = blockIdx.x * 256 + threadIdx.x;
  if (t >= kT) return;
#pragma unroll
  for (int k = 0; k < 2; ++k) {
    int e = tok_e[t * 2 + k];
    int pos = off[e] + atomicAdd(&cursor[e], 1);
    slot_token[pos]  = t;
    slot_weight[pos] = tok_w[t * 2 + k];
    token_slots[t * 2 + k] = pos;
  }
}

// ===================== staged-pipeline kernels ==============================

// D0: transpose w1/w3 for experts 0-3. z = (e&3) + 4*sel, 8 slices x 256 tiles.
__global__ __launch_bounds__(256, 2) void tconv13_first_kernel(
    const float* __restrict__ w1s, const float* __restrict__ w3s,
    short* __restrict__ w13t) {
  __shared__ __align__(16) char smem[65536];
  const int s = blockIdx.z;
  tconv13_tile(smem, s & 3, s >> 2, blockIdx.x, w1s, w3s, w13t);
}

// D1: z<4 -> g1 GEMM experts 0-3; z=4,5 -> tconv13 experts 4-7.
__global__ __launch_bounds__(256, 2) void uber1_kernel(
    const short* __restrict__ hsb, short* __restrict__ w13t,
    const int* __restrict__ cnt, const int* __restrict__ off,
    const int* __restrict__ slot_token, short* __restrict__ inter,
    const float* __restrict__ w1s, const float* __restrict__ w3s) {
  __shared__ __align__(16) char smem[65536];
  if (blockIdx.z < 4) {
    g1_gemm_block(smem, blockIdx.z, blockIdx.y, blockIdx.x,
                  hsb, w13t, cnt, off, slot_token, inter);
  } else {
    const int s = (blockIdx.z - 4) * 4 + (blockIdx.y & 3);   // 0..7
    const int tile = (blockIdx.y >> 2) * 64 + blockIdx.x;    // 0..255
    tconv13_tile(smem, 4 + (s & 3), s >> 2, tile, w1s, w3s, w13t);
  }
}

// D2: z<4 -> g1 GEMM experts 4-7; z=4,5 -> w2 transpose.
__global__ __launch_bounds__(256, 3) void g1b_kernel(
    const short* __restrict__ hsb, const short* __restrict__ w13t,
    const int* __restrict__ cnt, const int* __restrict__ off,
    const int* __restrict__ slot_token, short* __restrict__ inter,
    const float* __restrict__ w2s, short* __restrict__ w2t) {
  __shared__ __align__(16) char smem[32768];
  if (blockIdx.z < 4) {
    g1_gemm_block(smem, blockIdx.z + 4, blockIdx.y, blockIdx.x,
                  hsb, w13t, cnt, off, slot_token, inter);
  } else {
    w2t_pair(smem, ((blockIdx.z - 4) * 16 + blockIdx.y) * 64 + blockIdx.x,
             w2s, w2t);
  }
}

// ============== sequential-path kernels (r8 fallback) =======================

template <int MODE>
__global__ __launch_bounds__(256) void tconv_v4(
    const float* __restrict__ s1, const float* __restrict__ s3,
    short* __restrict__ dst0) {
  constexpr int K = MODE ? kI : kH;
  constexpr int N = MODE ? kH : kI;
  const int z = blockIdx.z;
  const int e = z & 7, sel = z >> 3;
  const float* src = (MODE ? s1 : (sel ? s3 : s1)) + (size_t)e * kH * kI;
  const int tb = blockIdx.x;
  const int nb = (tb & (N / 128 - 1)) * 128;
  const int kb = (tb / (N / 128)) * 128;
  __shared__ __align__(16) float lds[128 * 128];
  const int tid = threadIdx.x;
#pragma unroll
  for (int p = 0; p < 16; ++p) {
    const int q = p * 256 + tid;
    const int k = q >> 5;
    const int nc = (q & 31) * 4;
    gload16(src + (size_t)(kb + k) * N + nb + nc, (char*)lds + (size_t)q * 16);
  }
  const int c = tid & 127;
  const int kh2 = tid >> 7;
  const int n = nb + c;
  size_t drow;
  if (MODE == 0) drow = (size_t)e * 8192 + ((n >> 5) * 64 + sel * 32 + (n & 31));
  else           drow = (size_t)e * kH + n;
  short* dbase = dst0 + drow * K + kb;
#define CONV_SUB(S, WAITSTR)                                                  \
  do {                                                                        \
    asm volatile(WAITSTR ::: "memory");                                       \
    __builtin_amdgcn_s_barrier();                                             \
    __builtin_amdgcn_sched_barrier(0);                                        \
    _Pragma("unroll")                                                         \
    for (int i = 0; i < 2; ++i) {                                             \
      const int kc = (S) * 4 + kh2 * 2 + i;                                   \
      bf16x8 v;                                                               \
      _Pragma("unroll")                                                       \
      for (int j = 0; j < 8; ++j) v[j] = f2bf(lds[(kc * 8 + j) * 128 + c]);   \
      *(bf16x8*)(dbase + kc * 8) = v;                                         \
    }                                                                         \
  } while (0)
  CONV_SUB(0, "s_waitcnt vmcnt(12)");
  CONV_SUB(1, "s_waitcnt vmcnt(8)");
  CONV_SUB(2, "s_waitcnt vmcnt(4)");
  CONV_SUB(3, "s_waitcnt vmcnt(0)");
#undef CONV_SUB
}

// r8-style combined g1 (+w2t on z=8,9) for the sequential fallback.
__global__ __launch_bounds__(256, 3) void g1_kernel(
    const short* __restrict__ hsb, const short* __restrict__ w13t,
    const int* __restrict__ cnt, const int* __restrict__ off,
    const int* __restrict__ slot_token, short* __restrict__ inter,
    const float* __restrict__ w2s, short* __restrict__ w2t) {
  __shared__ __align__(16) char smem[32768];
  if (blockIdx.z >= 8) {
    w2t_pair(smem, ((blockIdx.z - 8) * 16 + blockIdx.y) * 64 + blockIdx.x,
             w2s, w2t);
    return;
  }
  g1_gemm_block(smem, blockIdx.z, blockIdx.y, blockIdx.x,
                hsb, w13t, cnt, off, slot_token, inter);
}

// --------- GEMM2: slot_out = w_slot * (inter @ w2), split-K=2, 16x16 --------
__global__ __launch_bounds__(256, 3) void g2_kernel(
    const short* __restrict__ inter, const short* __restrict__ w2t,
    const int* __restrict__ cnt, const int* __restrict__ off,
    const float* __restrict__ slot_weight, float* __restrict__ slot_out) {
  const int zz = blockIdx.z;
  const int e = zz & 7, half = zz >> 3;
  const int count = cnt[e];
  const int rb = blockIdx.y;
  if (rb * 128 >= count) return;
  const int slot0 = off[e] + rb * 128;
  const int mlim = ((count + 63) & ~63) - rb * 128;
  const int nb = blockIdx.x;                       // 0..7
  const int kbase = half * (kI / 2);

  __shared__ __align__(16) short As[128 * 64];
  __shared__ __align__(16) short Bs[128 * 64];

  const int tid = threadIdx.x;
  const int l = tid & 63, w = tid >> 6;
  const int wr = w >> 1, wc = w & 1;

  const int srow = l >> 3;
  const int sch  = (l & 7) ^ srow;
  const short* aptr[4];
  const short* bptr[4];
  unsigned sdst[4];
#pragma unroll
  for (int i = 0; i < 4; ++i) {
    const int q = w * 4 + i;
    const int row = q * 8 + srow;
    int sr = slot0 + row; if (sr >= kMaxSlots) sr = kMaxSlots - 1;
    aptr[i] = inter + (size_t)sr * kI + kbase + sch * 8;
    bptr[i] = w2t + ((size_t)e * kH + nb * 128 + row) * kI + kbase + sch * 8;
    sdst[i] = (unsigned)(q * 1024 + l * 16);
  }

  f32x4 acc[4][4];
#pragma unroll
  for (int mi = 0; mi < 4; ++mi)
#pragma unroll
    for (int ni = 0; ni < 4; ++ni)
#pragma unroll
      for (int r = 0; r < 4; ++r) acc[mi][ni][r] = 0.f;

  const int r16 = l & 15, g = l >> 4;

  for (int t = 0; t < (kI / 2) / 64; ++t) {
    const int k0 = t * 64;
#pragma unroll
    for (int i = 0; i < 4; ++i) {
      gload16(aptr[i] + k0, (char*)As + sdst[i]);
      gload16(bptr[i] + k0, (char*)Bs + sdst[i]);
    }
    __syncthreads();
#pragma unroll
    for (int kk = 0; kk < 2; ++kk) {
      const int chunk = kk * 4 + g;
      bf16x8 af[4], bf[4];
#pragma unroll
      for (int mi = 0; mi < 4; ++mi) {
        const int m = wr * 64 + mi * 16 + r16;
        af[mi] = *(const bf16x8*)((const char*)As + m * 128 + ((chunk ^ (m & 7)) * 16));
      }
#pragma unroll
      for (int ni = 0; ni < 4; ++ni) {
        const int n = wc * 64 + ni * 16 + r16;
        bf[ni] = *(const bf16x8*)((const char*)Bs + n * 128 + ((chunk ^ (n & 7)) * 16));
      }
#pragma unroll
      for (int mi = 0; mi < 4; ++mi)
#pragma unroll
        for (int ni = 0; ni < 4; ++ni)
          acc[mi][ni] = __builtin_amdgcn_mfma_f32_16x16x32_bf16(
              af[mi], bf[ni], acc[mi][ni], 0, 0, 0);
    }
    __syncthreads();
  }

#pragma unroll
  for (int mi = 0; mi < 4; ++mi)
#pragma unroll
    for (int r = 0; r < 4; ++r) {
      const int m = wr * 64 + mi * 16 + g * 4 + r;
      if (m < mlim) {
        const float sw = slot_weight[slot0 + m];
        const size_t orow = ((size_t)half * kMaxSlots + slot0 + m) * kH;
#pragma unroll
        for (int ni = 0; ni < 4; ++ni)
          slot_out[orow + nb * 128 + wc * 64 + ni * 16 + r16] =
              sw * acc[mi][ni][r];
      }
    }
}

__global__ __launch_bounds__(256) void combine4_kernel(
    const float* __restrict__ slot_out, const int* __restrict__ token_slots,
    float* __restrict__ out) {
  int idx = blockIdx.x * 256 + threadIdx.x;
  int t = idx >> 8;
  int c = (idx & 255) * 4;
  int s0 = token_slots[t * 2];
  int s1 = token_slots[t * 2 + 1];
  const size_t HS = (size_t)kMaxSlots * kH;
  float4 a = *(const float4*)(slot_out + (size_t)s0 * kH + c);
  float4 b = *(const float4*)(slot_out + (size_t)s1 * kH + c);
  float4 a2 = *(const float4*)(slot_out + HS + (size_t)s0 * kH + c);
  float4 b2 = *(const float4*)(slot_out + HS + (size_t)s1 * kH + c);
  float4 o;
  o.x = a.x + b.x + a2.x + b2.x; o.y = a.y + b.y + a2.y + b2.y;
  o.z = a.z + b.z + a2.z + b2.z; o.w = a.w + b.w + a2.w + b2.w;
  *(float4*)(out + (size_t)t * kH + c) = o;
}

// ===================== fallback path (r1, in-loop convert) ==================
__global__ __launch_bounds__(256) void fb_mlp1(
    const float* __restrict__ hs,
    const float* __restrict__ w1s, const float* __restrict__ w3s,
    const int* __restrict__ cnt, const int* __restrict__ off,
    const int* __restrict__ slot_token, short* __restrict__ inter) {
  const int e = blockIdx.z;
  const int count = cnt[e];
  const int rb = blockIdx.y;
  if (rb * 64 >= count) return;
  const int slot0 = off[e] + rb * 64;
  const int nb = blockIdx.x * 128;
  __shared__ __align__(16) short As[4 * 64 * 8];
  __shared__ __align__(16) short Bs[2][4 * 128 * 8];
  const int tid  = threadIdx.x;
  const int lane = tid & 63;
  const int wid  = tid >> 6;
  const int wr = wid >> 1, wc = wid & 1;
  const int am = tid & 63, akb = tid >> 6;
  int tok = slot_token[slot0 + am];
  if (tok < 0) tok = 0;
  const float* arow = hs + (size_t)tok * kH + akb * 8;
  const int which = tid >> 7;
  const int bn0 = (tid & 31) * 4;
  const int bkb = (tid >> 5) & 3;
  const float* wbase = (which ? w3s : w1s) +
      (size_t)e * kH * kI + (size_t)(bkb * 8) * kI + nb + bn0;
  char* bdstp = (char*)&Bs[which][0];
  f32x4 acc[2][2][4];
#pragma unroll
  for (int s = 0; s < 2; ++s)
#pragma unroll
    for (int mi = 0; mi < 2; ++mi)
#pragma unroll
      for (int ni = 0; ni < 4; ++ni)
#pragma unroll
        for (int r = 0; r < 4; ++r) acc[s][mi][ni][r] = 0.f;
  const int g = lane >> 4, r16 = lane & 15;
  for (int k0 = 0; k0 < kH; k0 += 32) {
    float4 a0 = *(const float4*)(arow + k0);
    float4 a1 = *(const float4*)(arow + k0 + 4);
    bf16x8 av;
    av[0] = f2bf(a0.x); av[1] = f2bf(a0.y); av[2] = f2bf(a0.z); av[3] = f2bf(a0.w);
    av[4] = f2bf(a1.x); av[5] = f2bf(a1.y); av[6] = f2bf(a1.z); av[7] = f2bf(a1.w);
    *(bf16x8*)&As[(akb * 64 + am) * 8] = av;
    {
      const float* bp = wbase + (size_t)k0 * kI;
      float4 v[8];
#pragma unroll
      for (int j = 0; j < 8; ++j) v[j] = *(const float4*)(bp + (size_t)j * kI);
      const float* vf = (const float*)v;
#pragma unroll
      for (int i = 0; i < 4; ++i) {
        bf16x8 w;
#pragma unroll
        for (int j = 0; j < 8; ++j) w[j] = f2bf(vf[j * 4 + i]);
        int n = bn0 + i;
        unsigned ba = (unsigned)((bkb * 128 + n) * 16) ^ ((((unsigned)n >> 3) & 7u) << 4);
        *(bf16x8*)(bdstp + ba) = w;
      }
    }
    __syncthreads();
    bf16x8 af[2], bfr[2][4];
#pragma unroll
    for (int mi = 0; mi < 2; ++mi)
      af[mi] = *(const bf16x8*)&As[(g * 64 + wr * 32 + mi * 16 + r16) * 8];
#pragma unroll
    for (int s = 0; s < 2; ++s)
#pragma unroll
      for (int ni = 0; ni < 4; ++ni) {
        int n = wc * 64 + ni * 16 + r16;
        unsigned ba = (unsigned)((g * 128 + n) * 16) ^ ((((unsigned)n >> 3) & 7u) << 4);
        bfr[s][ni] = *(const bf16x8*)((char*)&Bs[s][0] + ba);
      }
#pragma unroll
    for (int s = 0; s < 2; ++s)
#pragma unroll
      for (int mi = 0; mi < 2; ++mi)
#pragma unroll
        for (int ni = 0; ni < 4; ++ni)
          acc[s][mi][ni] = __builtin_amdgcn_mfma_f32_16x16x32_bf16(
              af[mi], bfr[s][ni], acc[s][mi][ni], 0, 0, 0);
    __syncthreads();
  }
#pragma unroll
  for (int mi = 0; mi < 2; ++mi)
#pragma unroll
    for (int ni = 0; ni < 4; ++ni)
#pragma unroll
      for (int r = 0; r < 4; ++r) {
        float h1 = acc[0][mi][ni][r];
        float h3 = acc[1][mi][ni][r];
        float y = h1 / (1.f + expf(-h1)) * h3;
        int m = wr * 32 + mi * 16 + g * 4 + r;
        int n = nb + wc * 64 + ni * 16 + r16;
        inter[(size_t)(slot0 + m) * kI + n] = f2bf(y);
      }
}

__global__ __launch_bounds__(256) void fb_mlp2(
    const short* __restrict__ inter, const float* __restrict__ w2s,
    const int* __restrict__ cnt, const int* __restrict__ off,
    const float* __restrict__ slot_weight, float* __restrict__ slot_out) {
  const int e = blockIdx.z;
  const int count = cnt[e];
  const int rb = blockIdx.y;
  if (rb * 64 >= count) return;
  const int slot0 = off[e] + rb * 64;
  const int nb = blockIdx.x * 128;
  __shared__ __align__(16) short As[8 * 64 * 8];
  __shared__ __align__(16) short Bs[8 * 128 * 8];
  const int tid  = threadIdx.x;
  const int lane = tid & 63;
  const int wid  = tid >> 6;
  const int wr = wid >> 1, wc = wid & 1;
  const int am = tid & 63, akb = tid >> 6;
  const short* arow = inter + (size_t)(slot0 + am) * kI;
  const int bn0 = (tid & 31) * 4;
  const int bkb = tid >> 5;
  const float* wbase = w2s + (size_t)e * kI * kH + (size_t)(bkb * 8) * kH + nb + bn0;
  f32x4 acc[2][4];
#pragma unroll
  for (int mi = 0; mi < 2; ++mi)
#pragma unroll
    for (int ni = 0; ni < 4; ++ni)
#pragma unroll
      for (int r = 0; r < 4; ++r) acc[mi][ni][r] = 0.f;
  const int g = lane >> 4, r16 = lane & 15;
  for (int k0 = 0; k0 < kI; k0 += 64) {
    bf16x8 x0 = *(const bf16x8*)(arow + k0 + akb * 8);
    bf16x8 x1 = *(const bf16x8*)(arow + k0 + (akb + 4) * 8);
    *(bf16x8*)&As[(akb * 64 + am) * 8] = x0;
    *(bf16x8*)&As[((akb + 4) * 64 + am) * 8] = x1;
    {
      const float* bp = wbase + (size_t)k0 * kH;
      float4 v[8];
#pragma unroll
      for (int j = 0; j < 8; ++j) v[j] = *(const float4*)(bp + (size_t)j * kH);
      const float* vf = (const float*)v;
#pragma unroll
      for (int i = 0; i < 4; ++i) {
        bf16x8 w;
#pragma unroll
        for (int j = 0; j < 8; ++j) w[j] = f2bf(vf[j * 4 + i]);
        int n = bn0 + i;
        unsigned ba = (unsigned)((bkb * 128 + n) * 16) ^ ((((unsigned)n >> 3) & 7u) << 4);
        *(bf16x8*)((char*)&Bs[0] + ba) = w;
      }
    }
    __syncthreads();
#pragma unroll
    for (int kk = 0; kk < 2; ++kk) {
      bf16x8 af[2], bfr[4];
#pragma unroll
      for (int mi = 0; mi < 2; ++mi)
        af[mi] = *(const bf16x8*)&As[((kk * 4 + g) * 64 + wr * 32 + mi * 16 + r16) * 8];
#pragma unroll
      for (int ni = 0; ni < 4; ++ni) {
        int n = wc * 64 + ni * 16 + r16;
        unsigned ba = (unsigned)(((kk * 4 + g) * 128 + n) * 16) ^ ((((unsigned)n >> 3) & 7u) << 4);
        bfr[ni] = *(const bf16x8*)((char*)&Bs[0] + ba);
      }
#pragma unroll
      for (int mi = 0; mi < 2; ++mi)
#pragma unroll
        for (int ni = 0; ni < 4; ++ni)
          acc[mi][ni] = __builtin_amdgcn_mfma_f32_16x16x32_bf16(
              af[mi], bfr[ni], acc[mi][ni], 0, 0, 0);
    }
    __syncthreads();
  }
  float sw[2][4];
#pragma unroll
  for (int mi = 0; mi < 2; ++mi)
#pragma unroll
    for (int r = 0; r < 4; ++r)
      sw[mi][r] = slot_weight[slot0 + wr * 32 + mi * 16 + g * 4 + r];
#pragma unroll
  for (int mi = 0; mi < 2; ++mi)
#pragma unroll
    for (int ni = 0; ni < 4; ++ni)
#pragma unroll
      for (int r = 0; r < 4; ++r) {
        int m = wr * 32 + mi * 16 + g * 4 + r;
        int n = nb + wc * 64 + ni * 16 + r16;
        slot_out[(size_t)(slot0 + m) * kH + n] = sw[mi][r] * acc[mi][ni][r];
      }
}

__global__ __launch_bounds__(256) void fb_combine(
    const float* __restrict__ slot_out, const int* __restrict__ token_slots,
    float* __restrict__ out) {
  int idx = blockIdx.x * 256 + threadIdx.x;
  int t = idx >> 8;
  int c = (idx & 255) * 4;
  int s0 = token_slots[t * 2];
  int s1 = token_slots[t * 2 + 1];
  float4 a = *(const float4*)(slot_out + (size_t)s0 * kH + c);
  float4 b = *(const float4*)(slot_out + (size_t)s1 * kH + c);
  float4 o;
  o.x = a.x + b.x; o.y = a.y + b.y; o.z = a.z + b.z; o.w = a.w + b.w;
  *(float4*)(out + (size_t)t * kH + c) = o;
}

// ============================== launcher ====================================
extern "C" void kernel_launch(void* const* d_in, const int* in_sizes, int n_in,
                              void* d_out, int out_size, void* d_ws, size_t ws_size,
                              hipStream_t stream) {
  (void)in_sizes; (void)n_in; (void)out_size;
  const float* hs  = (const float*)d_in[0];
  const float* gw  = (const float*)d_in[1];
  const float* w1s = (const float*)d_in[2];
  const float* w2s = (const float*)d_in[3];
  const float* w3s = (const float*)d_in[4];
  float* out = (float*)d_out;
  char* ws = (char*)d_ws;

  // shared control region
  int*   cnt         = (int*)(ws + 0);
  int*   cursor      = (int*)(ws + 64);
  int*   off         = (int*)(ws + 128);
  int*   tok_e       = (int*)(ws + 256);
  float* tok_w       = (float*)(ws + 16640);
  int*   token_slots = (int*)(ws + 33024);
  int*   slot_token  = (int*)(ws + 49408);
  float* slot_weight = (float*)(ws + 68352);

  constexpr size_t OFF_HSB     = 131072;
  constexpr size_t OFF_W13T    = OFF_HSB + (size_t)kT * kH * 2;     // 4,325,376
  constexpr size_t SZ_W13T     = (size_t)kNE * 8192 * kH * 2;       // 134,217,728
  constexpr size_t OFF_INTER   = OFF_W13T + SZ_W13T;                // 138,543,104
  constexpr size_t SZ_INTER    = (size_t)kMaxSlots * kI * 2;        // 37,748,736
  constexpr size_t NEED        = OFF_INTER + SZ_INTER;              // 176,291,840
  constexpr size_t OFF_W2T_OVL = OFF_W13T;                          // overlay (seq path)
  constexpr size_t OFF_SLOTOUT = OFF_W13T + (size_t)kNE * kH * kI * 2; // 71,434,240
  constexpr size_t SZ_W2T      = (size_t)kNE * kH * kI * 2;         // 67,108,864
  constexpr size_t OFF_W2T2    = NEED;
  constexpr size_t NEED2       = NEED + SZ_W2T;                     // 243,400,704

  hipMemsetAsync(ws, 0, 256, stream);

  if (ws_size >= NEED) {
    short* hsb      = (short*)(ws + OFF_HSB);
    short* w13t     = (short*)(ws + OFF_W13T);
    short* inter    = (short*)(ws + OFF_INTER);
    float* slot_out = (float*)(ws + OFF_SLOTOUT);
    const bool ovl  = (ws_size >= NEED2);
    short* w2t      = (short*)(ws + (ovl ? OFF_W2T2 : OFF_W2T_OVL));

    router_convhs_kernel<<<kT / 4 + kT * kH / 8 / 256, 256, 0, stream>>>(
        hs, gw, cnt, tok_e, tok_w, hsb);
    offsets_kernel<<<1, 256, 0, stream>>>(cnt, off, slot_token, slot_weight);
    assign_kernel<<<kT / 256, 256, 0, stream>>>(tok_e, tok_w, off, cursor,
                                                slot_token, slot_weight, token_slots);
    if (ovl) {
      // staged pipeline: tconv(0-3) -> [g1(0-3) || tconv(4-7)] -> [g1(4-7) || w2t]
      tconv13_first_kernel<<<dim3(256, 1, 8), 256, 0, stream>>>(w1s, w3s, w13t);
      uber1_kernel<<<dim3(64, 16, 6), 256, 0, stream>>>(
          hsb, w13t, cnt, off, slot_token, inter, w1s, w3s);
      g1b_kernel<<<dim3(64, 16, 6), 256, 0, stream>>>(
          hsb, w13t, cnt, off, slot_token, inter, w2s, w2t);
    } else {
      // r8 sequential: full tconv13, then g1 (w2t overlaid after g1 via extra z)
      tconv_v4<0><<<dim3(256, 1, 16), 256, 0, stream>>>(w1s, w3s, w13t);
      g1_kernel<<<dim3(64, 16, 8), 256, 0, stream>>>(
          hsb, w13t, cnt, off, slot_token, inter, w2s, w2t);
      tconv_v4<1><<<dim3(256, 1, 8), 256, 0, stream>>>(w2s, nullptr, w2t);
    }
    g2_kernel<<<dim3(kH / 128, kT / 128, kNE * 2), 256, 0, stream>>>(
        inter, w2t, cnt, off, slot_weight, slot_out);
    combine4_kernel<<<(kT * kH / 4) / 256, 256, 0, stream>>>(slot_out, token_slots, out);
  } else {
    // fallback: r1 layout
    float* slot_out = (float*)(ws + 131072);
    short* inter    = (short*)(ws + 131072 + 18874368);
    router_convhs_kernel<<<kT / 4, 256, 0, stream>>>(
        hs, gw, cnt, tok_e, tok_w, (short*)(ws + OFF_HSB));
    offsets_kernel<<<1, 256, 0, stream>>>(cnt, off, slot_token, slot_weight);
    assign_kernel<<<kT / 256, 256, 0, stream>>>(tok_e, tok_w, off, cursor,
                                                slot_token, slot_weight, token_slots);
    fb_mlp1<<<dim3(kI / 128, kT / 64, kNE), 256, 0, stream>>>(
        hs, w1s, w3s, cnt, off, slot_token, inter);
    fb_mlp2<<<dim3(kH / 128, kT / 64, kNE), 256, 0, stream>>>(
        inter, w2s, cnt, off, slot_weight, slot_out);
    fb_combine<<<(kT * kH / 4) / 256, 256, 0, stream>>>(slot_out, token_slots, out);
  }
}

// Round 10
// 385.241 us; speedup vs baseline: 1.0064x; 1.0064x over previous
//
#include <hip/hip_runtime.h>
#include <hip/hip_bf16.h>
#include <math.h>

// MoE: 8 experts, top-2, H=1024, I=4096, T=2048. f32 in/out, bf16 MFMA inside.
// Round 10: r9 staged pipeline with the occupancy fix — ALL pipeline kernels
// use 32KB LDS / (256,3): tconv13 tiles shrunk to 64k x 128n (BW is
// tile-size-invariant per r4/r5/r6). D0: tconv13(e0-3); D1: g1(e0-3)||tconv13(e4-7);
// D2: g1(e4-7)||w2t; D3: g2; D4: combine. Inner loops byte-identical to r8.
constexpr int kNE = 8;
constexpr int kH  = 1024;
constexpr int kI  = 4096;
constexpr int kT  = 2048;
constexpr int kMaxSlots = kT * 2 + kNE * 64;   // 4608
constexpr int kSlotPad  = kMaxSlots + 128;

typedef short bf16x8 __attribute__((ext_vector_type(8)));
typedef float f32x4  __attribute__((ext_vector_type(4)));

__device__ __forceinline__ short f2bf(float f) {
  union { float f; unsigned u; } v; v.f = f;
  unsigned r = v.u + 0x7fffu + ((v.u >> 16) & 1u);   // RNE
  return (short)(r >> 16);
}

__device__ __forceinline__ void gload16(const void* g, void* lds) {
  __builtin_amdgcn_global_load_lds(
      (const __attribute__((address_space(1))) void*)g,
      (__attribute__((address_space(3))) void*)lds, 16, 0, 0);
}

// ================= shared device building blocks ============================

// 32KB w1/w3 transpose tile (64k x 128n), counted-vmcnt drain.
// tile in 0..511: nb = (tile&31)*128, kb = (tile>>5)*64.
__device__ __forceinline__ void tconv13_tile32(
    char* smemraw, int e, int sel, int tile,
    const float* __restrict__ w1s, const float* __restrict__ w3s,
    short* __restrict__ w13t) {
  float* lds = (float*)smemraw;                    // [64k][128n]
  const float* src = (sel ? w3s : w1s) + (size_t)e * kH * kI;
  const int nb = (tile & 31) * 128;
  const int kb = (tile >> 5) * 64;
  const int tid = threadIdx.x;
#pragma unroll
  for (int p = 0; p < 8; ++p) {
    const int q = p * 256 + tid;                   // 16B granule, 2048 total
    const int k = q >> 5;
    const int nc = (q & 31) * 4;
    gload16(src + (size_t)(kb + k) * kI + nb + nc, (char*)lds + (size_t)q * 16);
  }
  const int c = tid & 127;
  const int kh2 = tid >> 7;
  const int n = nb + c;
  const size_t drow = (size_t)e * 8192 + ((n >> 5) * 64 + sel * 32 + (n & 31));
  short* dbase = w13t + drow * kH + kb;
#define CONV_SUB32(S, WAITSTR)                                                \
  do {                                                                        \
    asm volatile(WAITSTR ::: "memory");                                       \
    __builtin_amdgcn_s_barrier();                                             \
    __builtin_amdgcn_sched_barrier(0);                                        \
    {                                                                         \
      const int kc = (S) * 2 + kh2;                                           \
      bf16x8 v;                                                               \
      _Pragma("unroll")                                                       \
      for (int j = 0; j < 8; ++j) v[j] = f2bf(lds[(kc * 8 + j) * 128 + c]);   \
      *(bf16x8*)(dbase + kc * 8) = v;                                         \
    }                                                                         \
  } while (0)
  CONV_SUB32(0, "s_waitcnt vmcnt(6)");
  CONV_SUB32(1, "s_waitcnt vmcnt(4)");
  CONV_SUB32(2, "s_waitcnt vmcnt(2)");
  CONV_SUB32(3, "s_waitcnt vmcnt(0)");
#undef CONV_SUB32
}

// w2 transpose pair (two 128k x 64n tiles, 32KB LDS). dst: w2t [E][1024][4096].
__device__ __forceinline__ void w2t_pair(
    char* smemraw, int bt, const float* __restrict__ w2s,
    short* __restrict__ w2t) {
  float* tile = (float*)smemraw;
  const int tid = threadIdx.x;
#pragma unroll 1
  for (int s = 0; s < 2; ++s) {
    const int t = bt * 2 + s;                       // 0..4095
    const int e2 = t >> 9;
    const int r = t & 511;
    const int kbT = (r >> 4) * 128;
    const int nbT = (r & 15) * 64;
    const float* src = w2s + ((size_t)e2 * kI + kbT) * kH + nbT;
    if (s) __syncthreads();                         // LDS reuse WAR
#pragma unroll
    for (int p = 0; p < 8; ++p) {
      const int q = p * 256 + tid;
      const int k = q >> 4;
      const int nc = (q & 15) * 4;
      gload16(src + (size_t)k * kH + nc, (char*)tile + q * 16);
    }
    __syncthreads();                                // drains vmcnt
    const int c = tid & 63;
    const int kw = tid >> 6;
    short* drow = w2t + ((size_t)e2 * kH + nbT + c) * kI + kbT;
#pragma unroll
    for (int i = 0; i < 4; ++i) {
      const int kc = kw * 4 + i;
      bf16x8 v;
#pragma unroll
      for (int j = 0; j < 8; ++j) v[j] = f2bf(tile[(kc * 8 + j) * 64 + c]);
      *(bf16x8*)(drow + kc * 8) = v;
    }
  }
}

// GEMM1 block: 128m x 128pc, 4 waves, BK=64, 32KB LDS (r5-r8 verified loop).
__device__ __forceinline__ void g1_gemm_block(
    char* smem, int e, int rb, int nb,
    const short* __restrict__ hsb, const short* __restrict__ w13t,
    const int* __restrict__ cnt, const int* __restrict__ off,
    const int* __restrict__ slot_token, short* __restrict__ inter) {
  const int count = cnt[e];
  if (rb * 128 >= count) return;
  const int slot0 = off[e] + rb * 128;
  const int mlim = ((count + 63) & ~63) - rb * 128;

  short* As = (short*)smem;                         // 16KB [row][slot]
  short* Bs = (short*)(smem + 16384);               // 16KB
  const int tid = threadIdx.x;
  const int l = tid & 63, w = tid >> 6;
  const int wr = w >> 1, wc = w & 1;

  const int srow = l >> 3;
  const int sch  = (l & 7) ^ srow;
  const short* aptr[4];
  const short* bptr[4];
  unsigned sdst[4];
#pragma unroll
  for (int i = 0; i < 4; ++i) {
    const int q = w * 4 + i;
    const int row = q * 8 + srow;
    int tok = slot_token[slot0 + row]; if (tok < 0) tok = 0;
    aptr[i] = hsb + (size_t)tok * kH + sch * 8;
    bptr[i] = w13t + ((size_t)e * 8192 + nb * 128 + row) * kH + sch * 8;
    sdst[i] = (unsigned)(q * 1024 + l * 16);
  }

  f32x4 acc[4][4];
#pragma unroll
  for (int mi = 0; mi < 4; ++mi)
#pragma unroll
    for (int ni = 0; ni < 4; ++ni)
#pragma unroll
      for (int r = 0; r < 4; ++r) acc[mi][ni][r] = 0.f;

  const int r16 = l & 15, g = l >> 4;

  for (int t = 0; t < kH / 64; ++t) {
    const int k0 = t * 64;
#pragma unroll
    for (int i = 0; i < 4; ++i) {
      gload16(aptr[i] + k0, (char*)As + sdst[i]);
      gload16(bptr[i] + k0, (char*)Bs + sdst[i]);
    }
    __syncthreads();
#pragma unroll
    for (int kk = 0; kk < 2; ++kk) {
      const int chunk = kk * 4 + g;
      bf16x8 af[4], bf[4];
#pragma unroll
      for (int mi = 0; mi < 4; ++mi) {
        const int m = wr * 64 + mi * 16 + r16;
        af[mi] = *(const bf16x8*)((const char*)As + m * 128 + ((chunk ^ (m & 7)) * 16));
      }
#pragma unroll
      for (int ni = 0; ni < 4; ++ni) {
        const int n = wc * 64 + ni * 16 + r16;
        bf[ni] = *(const bf16x8*)((const char*)Bs + n * 128 + ((chunk ^ (n & 7)) * 16));
      }
#pragma unroll
      for (int mi = 0; mi < 4; ++mi)
#pragma unroll
        for (int ni = 0; ni < 4; ++ni)
          acc[mi][ni] = __builtin_amdgcn_mfma_f32_16x16x32_bf16(
              af[mi], bf[ni], acc[mi][ni], 0, 0, 0);
    }
    __syncthreads();
  }

  const int colb = (nb * 2 + wc) * 32;
#pragma unroll
  for (int mi = 0; mi < 4; ++mi)
#pragma unroll
    for (int r = 0; r < 4; ++r) {
      const int m = wr * 64 + mi * 16 + g * 4 + r;
      if (m < mlim) {
#pragma unroll
        for (int ni = 0; ni < 2; ++ni) {
          float h1 = acc[mi][ni][r];
          float h3 = acc[mi][ni + 2][r];
          float y = h1 / (1.f + expf(-h1)) * h3;
          inter[(size_t)(slot0 + m) * kI + colb + ni * 16 + r16] = f2bf(y);
        }
      }
    }
}

// ========================= small kernels ====================================

__global__ __launch_bounds__(256) void router_convhs_kernel(
    const float* __restrict__ hs, const float* __restrict__ gw,
    int* __restrict__ cnt, int* __restrict__ tok_e, float* __restrict__ tok_w,
    short* __restrict__ hsb) {
  if (blockIdx.x >= kT / 4) {
    const int idx = (blockIdx.x - kT / 4) * 256 + threadIdx.x;
    const float* p = hs + (size_t)idx * 8;
    float4 a = *(const float4*)p;
    float4 b = *(const float4*)(p + 4);
    bf16x8 w;
    w[0] = f2bf(a.x); w[1] = f2bf(a.y); w[2] = f2bf(a.z); w[3] = f2bf(a.w);
    w[4] = f2bf(b.x); w[5] = f2bf(b.y); w[6] = f2bf(b.z); w[7] = f2bf(b.w);
    *(bf16x8*)(hsb + (size_t)idx * 8) = w;
    return;
  }
  const int lane = threadIdx.x & 63;
  const int wid  = threadIdx.x >> 6;
  const int t = blockIdx.x * 4 + wid;
  const float* hrow = hs + (size_t)t * kH;
  float acc[kNE];
#pragma unroll
  for (int e = 0; e < kNE; ++e) acc[e] = 0.f;
  for (int i = lane; i < kH; i += 64) {
    float x = hrow[i];
    float4 g0 = *(const float4*)(gw + (size_t)i * kNE);
    float4 g1 = *(const float4*)(gw + (size_t)i * kNE + 4);
    acc[0] += x * g0.x; acc[1] += x * g0.y; acc[2] += x * g0.z; acc[3] += x * g0.w;
    acc[4] += x * g1.x; acc[5] += x * g1.y; acc[6] += x * g1.z; acc[7] += x * g1.w;
  }
#pragma unroll
  for (int o = 32; o; o >>= 1)
#pragma unroll
    for (int e = 0; e < kNE; ++e) acc[e] += __shfl_xor(acc[e], o);
  if (lane == 0) {
    int e0 = 0;
#pragma unroll
    for (int e = 1; e < kNE; ++e) if (acc[e] > acc[e0]) e0 = e;
    int e1 = (e0 == 0) ? 1 : 0;
#pragma unroll
    for (int e = 0; e < kNE; ++e) if (e != e0 && acc[e] > acc[e1]) e1 = e;
    float d  = acc[e1] - acc[e0];
    float w0 = 1.f / (1.f + expf(d));
    float w1 = 1.f / (1.f + expf(-d));
    atomicAdd(&cnt[e0], 1);
    atomicAdd(&cnt[e1], 1);
    tok_e[t * 2] = e0; tok_e[t * 2 + 1] = e1;
    tok_w[t * 2] = w0; tok_w[t * 2 + 1] = w1;
  }
}

__global__ __launch_bounds__(256) void offsets_kernel(
    const int* __restrict__ cnt, int* __restrict__ off,
    int* __restrict__ slot_token, float* __restrict__ slot_weight) {
  if (threadIdx.x == 0) {
    int o = 0;
#pragma unroll
    for (int e = 0; e < kNE; ++e) { off[e] = o; o += (cnt[e] + 63) & ~63; }
    off[kNE] = o;
  }
  for (int i = threadIdx.x; i < kSlotPad; i += 256) {
    slot_token[i]  = -1;
    slot_weight[i] = 0.f;
  }
}

__global__ __launch_bounds__(256) void assign_kernel(
    const int* __restrict__ tok_e, const float* __restrict__ tok_w,
    const int* __restrict__ off, int* __restrict__ cursor,
    int* __restrict__ slot_token, float* __restrict__ slot_weight,
    int* __restrict__ token_slots) {
  const int t = blockIdx.x * 256 + threadIdx.x;
  if (t >= kT) return;
#pragma unroll
  for (int k = 0; k < 2; ++k) {
    int e = tok_e[t * 2 + k];
    int pos = off[e] + atomicAdd(&cursor[e], 1);
    slot_token[pos]  = t;
    slot_weight[pos] = tok_w[t * 2 + k];
    token_slots[t * 2 + k] = pos;
  }
}

// ===================== staged-pipeline kernels (all 32KB) ===================

// D0: transpose w1/w3 for experts 0-3. z=e; idx=y*64+x -> sel=idx>>9, tile=idx&511.
__global__ __launch_bounds__(256) void tconv13_first_kernel(
    const float* __restrict__ w1s, const float* __restrict__ w3s,
    short* __restrict__ w13t) {
  __shared__ __align__(16) char smem[32768];
  const int idx = blockIdx.y * 64 + blockIdx.x;
  tconv13_tile32(smem, blockIdx.z, idx >> 9, idx & 511, w1s, w3s, w13t);
}

// D1: z<4 -> g1 GEMM experts 0-3; z=4..7 -> tconv13 expert z (4-7).
__global__ __launch_bounds__(256, 3) void uber1_kernel(
    const short* __restrict__ hsb, short* __restrict__ w13t,
    const int* __restrict__ cnt, const int* __restrict__ off,
    const int* __restrict__ slot_token, short* __restrict__ inter,
    const float* __restrict__ w1s, const float* __restrict__ w3s) {
  __shared__ __align__(16) char smem[32768];
  if (blockIdx.z < 4) {
    g1_gemm_block(smem, blockIdx.z, blockIdx.y, blockIdx.x,
                  hsb, w13t, cnt, off, slot_token, inter);
  } else {
    const int idx = blockIdx.y * 64 + blockIdx.x;          // 0..1023
    tconv13_tile32(smem, blockIdx.z, idx >> 9, idx & 511, w1s, w3s, w13t);
  }
}

// D2: z<4 -> g1 GEMM experts 4-7; z=4,5 -> w2 transpose.
__global__ __launch_bounds__(256, 3) void g1b_kernel(
    const short* __restrict__ hsb, const short* __restrict__ w13t,
    const int* __restrict__ cnt, const int* __restrict__ off,
    const int* __restrict__ slot_token, short* __restrict__ inter,
    const float* __restrict__ w2s, short* __restrict__ w2t) {
  __shared__ __align__(16) char smem[32768];
  if (blockIdx.z < 4) {
    g1_gemm_block(smem, blockIdx.z + 4, blockIdx.y, blockIdx.x,
                  hsb, w13t, cnt, off, slot_token, inter);
  } else {
    w2t_pair(smem, ((blockIdx.z - 4) * 16 + blockIdx.y) * 64 + blockIdx.x,
             w2s, w2t);
  }
}

// ============== sequential-path kernels (r8 fallback) =======================

template <int MODE>
__global__ __launch_bounds__(256) void tconv_v4(
    const float* __restrict__ s1, const float* __restrict__ s3,
    short* __restrict__ dst0) {
  constexpr int K = MODE ? kI : kH;
  constexpr int N = MODE ? kH : kI;
  const int z = blockIdx.z;
  const int e = z & 7, sel = z >> 3;
  const float* src = (MODE ? s1 : (sel ? s3 : s1)) + (size_t)e * kH * kI;
  const int tb = blockIdx.x;
  const int nb = (tb & (N / 128 - 1)) * 128;
  const int kb = (tb / (N / 128)) * 128;
  __shared__ __align__(16) float lds[128 * 128];
  const int tid = threadIdx.x;
#pragma unroll
  for (int p = 0; p < 16; ++p) {
    const int q = p * 256 + tid;
    const int k = q >> 5;
    const int nc = (q & 31) * 4;
    gload16(src + (size_t)(kb + k) * N + nb + nc, (char*)lds + (size_t)q * 16);
  }
  const int c = tid & 127;
  const int kh2 = tid >> 7;
  const int n = nb + c;
  size_t drow;
  if (MODE == 0) drow = (size_t)e * 8192 + ((n >> 5) * 64 + sel * 32 + (n & 31));
  else           drow = (size_t)e * kH + n;
  short* dbase = dst0 + drow * K + kb;
#define CONV_SUB(S, WAITSTR)                                                  \
  do {                                                                        \
    asm volatile(WAITSTR ::: "memory");                                       \
    __builtin_amdgcn_s_barrier();                                             \
    __builtin_amdgcn_sched_barrier(0);                                        \
    _Pragma("unroll")                                                         \
    for (int i = 0; i < 2; ++i) {                                             \
      const int kc = (S) * 4 + kh2 * 2 + i;                                   \
      bf16x8 v;                                                               \
      _Pragma("unroll")                                                       \
      for (int j = 0; j < 8; ++j) v[j] = f2bf(lds[(kc * 8 + j) * 128 + c]);   \
      *(bf16x8*)(dbase + kc * 8) = v;                                         \
    }                                                                         \
  } while (0)
  CONV_SUB(0, "s_waitcnt vmcnt(12)");
  CONV_SUB(1, "s_waitcnt vmcnt(8)");
  CONV_SUB(2, "s_waitcnt vmcnt(4)");
  CONV_SUB(3, "s_waitcnt vmcnt(0)");
#undef CONV_SUB
}

// r8-style combined g1 (+w2t on z=8,9) for the sequential fallback.
__global__ __launch_bounds__(256, 3) void g1_kernel(
    const short* __restrict__ hsb, const short* __restrict__ w13t,
    const int* __restrict__ cnt, const int* __restrict__ off,
    const int* __restrict__ slot_token, short* __restrict__ inter,
    const float* __restrict__ w2s, short* __restrict__ w2t) {
  __shared__ __align__(16) char smem[32768];
  if (blockIdx.z >= 8) {
    w2t_pair(smem, ((blockIdx.z - 8) * 16 + blockIdx.y) * 64 + blockIdx.x,
             w2s, w2t);
    return;
  }
  g1_gemm_block(smem, blockIdx.z, blockIdx.y, blockIdx.x,
                hsb, w13t, cnt, off, slot_token, inter);
}

// --------- GEMM2: slot_out = w_slot * (inter @ w2), split-K=2, 16x16 --------
__global__ __launch_bounds__(256, 3) void g2_kernel(
    const short* __restrict__ inter, const short* __restrict__ w2t,
    const int* __restrict__ cnt, const int* __restrict__ off,
    const float* __restrict__ slot_weight, float* __restrict__ slot_out) {
  const int zz = blockIdx.z;
  const int e = zz & 7, half = zz >> 3;
  const int count = cnt[e];
  const int rb = blockIdx.y;
  if (rb * 128 >= count) return;
  const int slot0 = off[e] + rb * 128;
  const int mlim = ((count + 63) & ~63) - rb * 128;
  const int nb = blockIdx.x;                       // 0..7
  const int kbase = half * (kI / 2);

  __shared__ __align__(16) short As[128 * 64];
  __shared__ __align__(16) short Bs[128 * 64];

  const int tid = threadIdx.x;
  const int l = tid & 63, w = tid >> 6;
  const int wr = w >> 1, wc = w & 1;

  const int srow = l >> 3;
  const int sch  = (l & 7) ^ srow;
  const short* aptr[4];
  const short* bptr[4];
  unsigned sdst[4];
#pragma unroll
  for (int i = 0; i < 4; ++i) {
    const int q = w * 4 + i;
    const int row = q * 8 + srow;
    int sr = slot0 + row; if (sr >= kMaxSlots) sr = kMaxSlots - 1;
    aptr[i] = inter + (size_t)sr * kI + kbase + sch * 8;
    bptr[i] = w2t + ((size_t)e * kH + nb * 128 + row) * kI + kbase + sch * 8;
    sdst[i] = (unsigned)(q * 1024 + l * 16);
  }

  f32x4 acc[4][4];
#pragma unroll
  for (int mi = 0; mi < 4; ++mi)
#pragma unroll
    for (int ni = 0; ni < 4; ++ni)
#pragma unroll
      for (int r = 0; r < 4; ++r) acc[mi][ni][r] = 0.f;

  const int r16 = l & 15, g = l >> 4;

  for (int t = 0; t < (kI / 2) / 64; ++t) {
    const int k0 = t * 64;
#pragma unroll
    for (int i = 0; i < 4; ++i) {
      gload16(aptr[i] + k0, (char*)As + sdst[i]);
      gload16(bptr[i] + k0, (char*)Bs + sdst[i]);
    }
    __syncthreads();
#pragma unroll
    for (int kk = 0; kk < 2; ++kk) {
      const int chunk = kk * 4 + g;
      bf16x8 af[4], bf[4];
#pragma unroll
      for (int mi = 0; mi < 4; ++mi) {
        const int m = wr * 64 + mi * 16 + r16;
        af[mi] = *(const bf16x8*)((const char*)As + m * 128 + ((chunk ^ (m & 7)) * 16));
      }
#pragma unroll
      for (int ni = 0; ni < 4; ++ni) {
        const int n = wc * 64 + ni * 16 + r16;
        bf[ni] = *(const bf16x8*)((const char*)Bs + n * 128 + ((chunk ^ (n & 7)) * 16));
      }
#pragma unroll
      for (int mi = 0; mi < 4; ++mi)
#pragma unroll
        for (int ni = 0; ni < 4; ++ni)
          acc[mi][ni] = __builtin_amdgcn_mfma_f32_16x16x32_bf16(
              af[mi], bf[ni], acc[mi][ni], 0, 0, 0);
    }
    __syncthreads();
  }

#pragma unroll
  for (int mi = 0; mi < 4; ++mi)
#pragma unroll
    for (int r = 0; r < 4; ++r) {
      const int m = wr * 64 + mi * 16 + g * 4 + r;
      if (m < mlim) {
        const float sw = slot_weight[slot0 + m];
        const size_t orow = ((size_t)half * kMaxSlots + slot0 + m) * kH;
#pragma unroll
        for (int ni = 0; ni < 4; ++ni)
          slot_out[orow + nb * 128 + wc * 64 + ni * 16 + r16] =
              sw * acc[mi][ni][r];
      }
    }
}

__global__ __launch_bounds__(256) void combine4_kernel(
    const float* __restrict__ slot_out, const int* __restrict__ token_slots,
    float* __restrict__ out) {
  int idx = blockIdx.x * 256 + threadIdx.x;
  int t = idx >> 8;
  int c = (idx & 255) * 4;
  int s0 = token_slots[t * 2];
  int s1 = token_slots[t * 2 + 1];
  const size_t HS = (size_t)kMaxSlots * kH;
  float4 a = *(const float4*)(slot_out + (size_t)s0 * kH + c);
  float4 b = *(const float4*)(slot_out + (size_t)s1 * kH + c);
  float4 a2 = *(const float4*)(slot_out + HS + (size_t)s0 * kH + c);
  float4 b2 = *(const float4*)(slot_out + HS + (size_t)s1 * kH + c);
  float4 o;
  o.x = a.x + b.x + a2.x + b2.x; o.y = a.y + b.y + a2.y + b2.y;
  o.z = a.z + b.z + a2.z + b2.z; o.w = a.w + b.w + a2.w + b2.w;
  *(float4*)(out + (size_t)t * kH + c) = o;
}

// ===================== fallback path (r1, in-loop convert) ==================
__global__ __launch_bounds__(256) void fb_mlp1(
    const float* __restrict__ hs,
    const float* __restrict__ w1s, const float* __restrict__ w3s,
    const int* __restrict__ cnt, const int* __restrict__ off,
    const int* __restrict__ slot_token, short* __restrict__ inter) {
  const int e = blockIdx.z;
  const int count = cnt[e];
  const int rb = blockIdx.y;
  if (rb * 64 >= count) return;
  const int slot0 = off[e] + rb * 64;
  const int nb = blockIdx.x * 128;
  __shared__ __align__(16) short As[4 * 64 * 8];
  __shared__ __align__(16) short Bs[2][4 * 128 * 8];
  const int tid  = threadIdx.x;
  const int lane = tid & 63;
  const int wid  = tid >> 6;
  const int wr = wid >> 1, wc = wid & 1;
  const int am = tid & 63, akb = tid >> 6;
  int tok = slot_token[slot0 + am];
  if (tok < 0) tok = 0;
  const float* arow = hs + (size_t)tok * kH + akb * 8;
  const int which = tid >> 7;
  const int bn0 = (tid & 31) * 4;
  const int bkb = (tid >> 5) & 3;
  const float* wbase = (which ? w3s : w1s) +
      (size_t)e * kH * kI + (size_t)(bkb * 8) * kI + nb + bn0;
  char* bdstp = (char*)&Bs[which][0];
  f32x4 acc[2][2][4];
#pragma unroll
  for (int s = 0; s < 2; ++s)
#pragma unroll
    for (int mi = 0; mi < 2; ++mi)
#pragma unroll
      for (int ni = 0; ni < 4; ++ni)
#pragma unroll
        for (int r = 0; r < 4; ++r) acc[s][mi][ni][r] = 0.f;
  const int g = lane >> 4, r16 = lane & 15;
  for (int k0 = 0; k0 < kH; k0 += 32) {
    float4 a0 = *(const float4*)(arow + k0);
    float4 a1 = *(const float4*)(arow + k0 + 4);
    bf16x8 av;
    av[0] = f2bf(a0.x); av[1] = f2bf(a0.y); av[2] = f2bf(a0.z); av[3] = f2bf(a0.w);
    av[4] = f2bf(a1.x); av[5] = f2bf(a1.y); av[6] = f2bf(a1.z); av[7] = f2bf(a1.w);
    *(bf16x8*)&As[(akb * 64 + am) * 8] = av;
    {
      const float* bp = wbase + (size_t)k0 * kI;
      float4 v[8];
#pragma unroll
      for (int j = 0; j < 8; ++j) v[j] = *(const float4*)(bp + (size_t)j * kI);
      const float* vf = (const float*)v;
#pragma unroll
      for (int i = 0; i < 4; ++i) {
        bf16x8 w;
#pragma unroll
        for (int j = 0; j < 8; ++j) w[j] = f2bf(vf[j * 4 + i]);
        int n = bn0 + i;
        unsigned ba = (unsigned)((bkb * 128 + n) * 16) ^ ((((unsigned)n >> 3) & 7u) << 4);
        *(bf16x8*)(bdstp + ba) = w;
      }
    }
    __syncthreads();
    bf16x8 af[2], bfr[2][4];
#pragma unroll
    for (int mi = 0; mi < 2; ++mi)
      af[mi] = *(const bf16x8*)&As[(g * 64 + wr * 32 + mi * 16 + r16) * 8];
#pragma unroll
    for (int s = 0; s < 2; ++s)
#pragma unroll
      for (int ni = 0; ni < 4; ++ni) {
        int n = wc * 64 + ni * 16 + r16;
        unsigned ba = (unsigned)((g * 128 + n) * 16) ^ ((((unsigned)n >> 3) & 7u) << 4);
        bfr[s][ni] = *(const bf16x8*)((char*)&Bs[s][0] + ba);
      }
#pragma unroll
    for (int s = 0; s < 2; ++s)
#pragma unroll
      for (int mi = 0; mi < 2; ++mi)
#pragma unroll
        for (int ni = 0; ni < 4; ++ni)
          acc[s][mi][ni] = __builtin_amdgcn_mfma_f32_16x16x32_bf16(
              af[mi], bfr[s][ni], acc[s][mi][ni], 0, 0, 0);
    __syncthreads();
  }
#pragma unroll
  for (int mi = 0; mi < 2; ++mi)
#pragma unroll
    for (int ni = 0; ni < 4; ++ni)
#pragma unroll
      for (int r = 0; r < 4; ++r) {
        float h1 = acc[0][mi][ni][r];
        float h3 = acc[1][mi][ni][r];
        float y = h1 / (1.f + expf(-h1)) * h3;
        int m = wr * 32 + mi * 16 + g * 4 + r;
        int n = nb + wc * 64 + ni * 16 + r16;
        inter[(size_t)(slot0 + m) * kI + n] = f2bf(y);
      }
}

__global__ __launch_bounds__(256) void fb_mlp2(
    const short* __restrict__ inter, const float* __restrict__ w2s,
    const int* __restrict__ cnt, const int* __restrict__ off,
    const float* __restrict__ slot_weight, float* __restrict__ slot_out) {
  const int e = blockIdx.z;
  const int count = cnt[e];
  const int rb = blockIdx.y;
  if (rb * 64 >= count) return;
  const int slot0 = off[e] + rb * 64;
  const int nb = blockIdx.x * 128;
  __shared__ __align__(16) short As[8 * 64 * 8];
  __shared__ __align__(16) short Bs[8 * 128 * 8];
  const int tid  = threadIdx.x;
  const int lane = tid & 63;
  const int wid  = tid >> 6;
  const int wr = wid >> 1, wc = wid & 1;
  const int am = tid & 63, akb = tid >> 6;
  const short* arow = inter + (size_t)(slot0 + am) * kI;
  const int bn0 = (tid & 31) * 4;
  const int bkb = tid >> 5;
  const float* wbase = w2s + (size_t)e * kI * kH + (size_t)(bkb * 8) * kH + nb + bn0;
  f32x4 acc[2][4];
#pragma unroll
  for (int mi = 0; mi < 2; ++mi)
#pragma unroll
    for (int ni = 0; ni < 4; ++ni)
#pragma unroll
      for (int r = 0; r < 4; ++r) acc[mi][ni][r] = 0.f;
  const int g = lane >> 4, r16 = lane & 15;
  for (int k0 = 0; k0 < kI; k0 += 64) {
    bf16x8 x0 = *(const bf16x8*)(arow + k0 + akb * 8);
    bf16x8 x1 = *(const bf16x8*)(arow + k0 + (akb + 4) * 8);
    *(bf16x8*)&As[(akb * 64 + am) * 8] = x0;
    *(bf16x8*)&As[((akb + 4) * 64 + am) * 8] = x1;
    {
      const float* bp = wbase + (size_t)k0 * kH;
      float4 v[8];
#pragma unroll
      for (int j = 0; j < 8; ++j) v[j] = *(const float4*)(bp + (size_t)j * kH);
      const float* vf = (const float*)v;
#pragma unroll
      for (int i = 0; i < 4; ++i) {
        bf16x8 w;
#pragma unroll
        for (int j = 0; j < 8; ++j) w[j] = f2bf(vf[j * 4 + i]);
        int n = bn0 + i;
        unsigned ba = (unsigned)((bkb * 128 + n) * 16) ^ ((((unsigned)n >> 3) & 7u) << 4);
        *(bf16x8*)((char*)&Bs[0] + ba) = w;
      }
    }
    __syncthreads();
#pragma unroll
    for (int kk = 0; kk < 2; ++kk) {
      bf16x8 af[2], bfr[4];
#pragma unroll
      for (int mi = 0; mi < 2; ++mi)
        af[mi] = *(const bf16x8*)&As[((kk * 4 + g) * 64 + wr * 32 + mi * 16 + r16) * 8];
#pragma unroll
      for (int ni = 0; ni < 4; ++ni) {
        int n = wc * 64 + ni * 16 + r16;
        unsigned ba = (unsigned)(((kk * 4 + g) * 128 + n) * 16) ^ ((((unsigned)n >> 3) & 7u) << 4);
        bfr[ni] = *(const bf16x8*)((char*)&Bs[0] + ba);
      }
#pragma unroll
      for (int mi = 0; mi < 2; ++mi)
#pragma unroll
        for (int ni = 0; ni < 4; ++ni)
          acc[mi][ni] = __builtin_amdgcn_mfma_f32_16x16x32_bf16(
              af[mi], bfr[ni], acc[mi][ni], 0, 0, 0);
    }
    __syncthreads();
  }
  float sw[2][4];
#pragma unroll
  for (int mi = 0; mi < 2; ++mi)
#pragma unroll
    for (int r = 0; r < 4; ++r)
      sw[mi][r] = slot_weight[slot0 + wr * 32 + mi * 16 + g * 4 + r];
#pragma unroll
  for (int mi = 0; mi < 2; ++mi)
#pragma unroll
    for (int ni = 0; ni < 4; ++ni)
#pragma unroll
      for (int r = 0; r < 4; ++r) {
        int m = wr * 32 + mi * 16 + g * 4 + r;
        int n = nb + wc * 64 + ni * 16 + r16;
        slot_out[(size_t)(slot0 + m) * kH + n] = sw[mi][r] * acc[mi][ni][r];
      }
}

__global__ __launch_bounds__(256) void fb_combine(
    const float* __restrict__ slot_out, const int* __restrict__ token_slots,
    float* __restrict__ out) {
  int idx = blockIdx.x * 256 + threadIdx.x;
  int t = idx >> 8;
  int c = (idx & 255) * 4;
  int s0 = token_slots[t * 2];
  int s1 = token_slots[t * 2 + 1];
  float4 a = *(const float4*)(slot_out + (size_t)s0 * kH + c);
  float4 b = *(const float4*)(slot_out + (size_t)s1 * kH + c);
  float4 o;
  o.x = a.x + b.x; o.y = a.y + b.y; o.z = a.z + b.z; o.w = a.w + b.w;
  *(float4*)(out + (size_t)t * kH + c) = o;
}

// ============================== launcher ====================================
extern "C" void kernel_launch(void* const* d_in, const int* in_sizes, int n_in,
                              void* d_out, int out_size, void* d_ws, size_t ws_size,
                              hipStream_t stream) {
  (void)in_sizes; (void)n_in; (void)out_size;
  const float* hs  = (const float*)d_in[0];
  const float* gw  = (const float*)d_in[1];
  const float* w1s = (const float*)d_in[2];
  const float* w2s = (const float*)d_in[3];
  const float* w3s = (const float*)d_in[4];
  float* out = (float*)d_out;
  char* ws = (char*)d_ws;

  // shared control region
  int*   cnt         = (int*)(ws + 0);
  int*   cursor      = (int*)(ws + 64);
  int*   off         = (int*)(ws + 128);
  int*   tok_e       = (int*)(ws + 256);
  float* tok_w       = (float*)(ws + 16640);
  int*   token_slots = (int*)(ws + 33024);
  int*   slot_token  = (int*)(ws + 49408);
  float* slot_weight = (float*)(ws + 68352);

  constexpr size_t OFF_HSB     = 131072;
  constexpr size_t OFF_W13T    = OFF_HSB + (size_t)kT * kH * 2;     // 4,325,376
  constexpr size_t SZ_W13T     = (size_t)kNE * 8192 * kH * 2;       // 134,217,728
  constexpr size_t OFF_INTER   = OFF_W13T + SZ_W13T;                // 138,543,104
  constexpr size_t SZ_INTER    = (size_t)kMaxSlots * kI * 2;        // 37,748,736
  constexpr size_t NEED        = OFF_INTER + SZ_INTER;              // 176,291,840
  constexpr size_t OFF_W2T_OVL = OFF_W13T;                          // overlay (seq path)
  constexpr size_t OFF_SLOTOUT = OFF_W13T + (size_t)kNE * kH * kI * 2; // 71,434,240
  constexpr size_t SZ_W2T      = (size_t)kNE * kH * kI * 2;         // 67,108,864
  constexpr size_t OFF_W2T2    = NEED;
  constexpr size_t NEED2       = NEED + SZ_W2T;                     // 243,400,704

  hipMemsetAsync(ws, 0, 256, stream);

  if (ws_size >= NEED) {
    short* hsb      = (short*)(ws + OFF_HSB);
    short* w13t     = (short*)(ws + OFF_W13T);
    short* inter    = (short*)(ws + OFF_INTER);
    float* slot_out = (float*)(ws + OFF_SLOTOUT);
    const bool ovl  = (ws_size >= NEED2);
    short* w2t      = (short*)(ws + (ovl ? OFF_W2T2 : OFF_W2T_OVL));

    router_convhs_kernel<<<kT / 4 + kT * kH / 8 / 256, 256, 0, stream>>>(
        hs, gw, cnt, tok_e, tok_w, hsb);
    offsets_kernel<<<1, 256, 0, stream>>>(cnt, off, slot_token, slot_weight);
    assign_kernel<<<kT / 256, 256, 0, stream>>>(tok_e, tok_w, off, cursor,
                                                slot_token, slot_weight, token_slots);
    if (ovl) {
      // staged pipeline, all 32KB: tconv(0-3) -> [g1(0-3) || tconv(4-7)]
      //                            -> [g1(4-7) || w2t] -> g2 -> combine
      tconv13_first_kernel<<<dim3(64, 16, 4), 256, 0, stream>>>(w1s, w3s, w13t);
      uber1_kernel<<<dim3(64, 16, 8), 256, 0, stream>>>(
          hsb, w13t, cnt, off, slot_token, inter, w1s, w3s);
      g1b_kernel<<<dim3(64, 16, 6), 256, 0, stream>>>(
          hsb, w13t, cnt, off, slot_token, inter, w2s, w2t);
    } else {
      // r8 sequential: full tconv13, then g1 (+w2t on z=8,9)
      tconv_v4<0><<<dim3(256, 1, 16), 256, 0, stream>>>(w1s, w3s, w13t);
      g1_kernel<<<dim3(64, 16, 10), 256, 0, stream>>>(
          hsb, w13t, cnt, off, slot_token, inter, w2s, w2t);
    }
    g2_kernel<<<dim3(kH / 128, kT / 128, kNE * 2), 256, 0, stream>>>(
        inter, w2t, cnt, off, slot_weight, slot_out);
    combine4_kernel<<<(kT * kH / 4) / 256, 256, 0, stream>>>(slot_out, token_slots, out);
  } else {
    // fallback: r1 layout
    float* slot_out = (float*)(ws + 131072);
    short* inter    = (short*)(ws + 131072 + 18874368);
    router_convhs_kernel<<<kT / 4, 256, 0, stream>>>(
        hs, gw, cnt, tok_e, tok_w, (short*)(ws + OFF_HSB));
    offsets_kernel<<<1, 256, 0, stream>>>(cnt, off, slot_token, slot_weight);
    assign_kernel<<<kT / 256, 256, 0, stream>>>(tok_e, tok_w, off, cursor,
                                                slot_token, slot_weight, token_slots);
    fb_mlp1<<<dim3(kI / 128, kT / 64, kNE), 256, 0, stream>>>(
        hs, w1s, w3s, cnt, off, slot_token, inter);
    fb_mlp2<<<dim3(kH / 128, kT / 64, kNE), 256, 0, stream>>>(
        inter, w2s, cnt, off, slot_weight, slot_out);
    fb_combine<<<(kT * kH / 4) / 256, 256, 0, stream>>>(slot_out, token_slots, out);
  }
}

// Round 11
// 376.217 us; speedup vs baseline: 1.0305x; 1.0240x over previous
//
#include <hip/hip_runtime.h>
#include <hip/hip_bf16.h>
#include <math.h>

// MoE: 8 experts, top-2, H=1024, I=4096, T=2048. f32 in/out, bf16 MFMA inside.
// Round 11: revert to r8 schedule (best measured, 373us); g2 rebuilt:
// no split-K + XCD-chunked block swizzle (T1) so nb-neighbor blocks sharing
// the inter A-panel land on one XCD's L2. Combine reads 2 slots.
constexpr int kNE = 8;
constexpr int kH  = 1024;
constexpr int kI  = 4096;
constexpr int kT  = 2048;
constexpr int kMaxSlots = kT * 2 + kNE * 64;   // 4608
constexpr int kSlotPad  = kMaxSlots + 128;

typedef short bf16x8 __attribute__((ext_vector_type(8)));
typedef float f32x4  __attribute__((ext_vector_type(4)));

__device__ __forceinline__ short f2bf(float f) {
  union { float f; unsigned u; } v; v.f = f;
  unsigned r = v.u + 0x7fffu + ((v.u >> 16) & 1u);   // RNE
  return (short)(r >> 16);
}

__device__ __forceinline__ void gload16(const void* g, void* lds) {
  __builtin_amdgcn_global_load_lds(
      (const __attribute__((address_space(1))) void*)g,
      (__attribute__((address_space(3))) void*)lds, 16, 0, 0);
}

// ================= shared device building blocks ============================

// w2 transpose pair (two 128k x 64n tiles, 32KB LDS). dst: w2t [E][1024][4096].
__device__ __forceinline__ void w2t_pair(
    char* smemraw, int bt, const float* __restrict__ w2s,
    short* __restrict__ w2t) {
  float* tile = (float*)smemraw;
  const int tid = threadIdx.x;
#pragma unroll 1
  for (int s = 0; s < 2; ++s) {
    const int t = bt * 2 + s;                       // 0..4095
    const int e2 = t >> 9;
    const int r = t & 511;
    const int kbT = (r >> 4) * 128;
    const int nbT = (r & 15) * 64;
    const float* src = w2s + ((size_t)e2 * kI + kbT) * kH + nbT;
    if (s) __syncthreads();                         // LDS reuse WAR
#pragma unroll
    for (int p = 0; p < 8; ++p) {
      const int q = p * 256 + tid;
      const int k = q >> 4;
      const int nc = (q & 15) * 4;
      gload16(src + (size_t)k * kH + nc, (char*)tile + q * 16);
    }
    __syncthreads();                                // drains vmcnt
    const int c = tid & 63;
    const int kw = tid >> 6;
    short* drow = w2t + ((size_t)e2 * kH + nbT + c) * kI + kbT;
#pragma unroll
    for (int i = 0; i < 4; ++i) {
      const int kc = kw * 4 + i;
      bf16x8 v;
#pragma unroll
      for (int j = 0; j < 8; ++j) v[j] = f2bf(tile[(kc * 8 + j) * 64 + c]);
      *(bf16x8*)(drow + kc * 8) = v;
    }
  }
}

// GEMM1 block: 128m x 128pc, 4 waves, BK=64, 32KB LDS (r5-r8 verified loop).
__device__ __forceinline__ void g1_gemm_block(
    char* smem, int e, int rb, int nb,
    const short* __restrict__ hsb, const short* __restrict__ w13t,
    const int* __restrict__ cnt, const int* __restrict__ off,
    const int* __restrict__ slot_token, short* __restrict__ inter) {
  const int count = cnt[e];
  if (rb * 128 >= count) return;
  const int slot0 = off[e] + rb * 128;
  const int mlim = ((count + 63) & ~63) - rb * 128;

  short* As = (short*)smem;                         // 16KB [row][slot]
  short* Bs = (short*)(smem + 16384);               // 16KB
  const int tid = threadIdx.x;
  const int l = tid & 63, w = tid >> 6;
  const int wr = w >> 1, wc = w & 1;

  const int srow = l >> 3;
  const int sch  = (l & 7) ^ srow;
  const short* aptr[4];
  const short* bptr[4];
  unsigned sdst[4];
#pragma unroll
  for (int i = 0; i < 4; ++i) {
    const int q = w * 4 + i;
    const int row = q * 8 + srow;
    int tok = slot_token[slot0 + row]; if (tok < 0) tok = 0;
    aptr[i] = hsb + (size_t)tok * kH + sch * 8;
    bptr[i] = w13t + ((size_t)e * 8192 + nb * 128 + row) * kH + sch * 8;
    sdst[i] = (unsigned)(q * 1024 + l * 16);
  }

  f32x4 acc[4][4];
#pragma unroll
  for (int mi = 0; mi < 4; ++mi)
#pragma unroll
    for (int ni = 0; ni < 4; ++ni)
#pragma unroll
      for (int r = 0; r < 4; ++r) acc[mi][ni][r] = 0.f;

  const int r16 = l & 15, g = l >> 4;

  for (int t = 0; t < kH / 64; ++t) {
    const int k0 = t * 64;
#pragma unroll
    for (int i = 0; i < 4; ++i) {
      gload16(aptr[i] + k0, (char*)As + sdst[i]);
      gload16(bptr[i] + k0, (char*)Bs + sdst[i]);
    }
    __syncthreads();
#pragma unroll
    for (int kk = 0; kk < 2; ++kk) {
      const int chunk = kk * 4 + g;
      bf16x8 af[4], bf[4];
#pragma unroll
      for (int mi = 0; mi < 4; ++mi) {
        const int m = wr * 64 + mi * 16 + r16;
        af[mi] = *(const bf16x8*)((const char*)As + m * 128 + ((chunk ^ (m & 7)) * 16));
      }
#pragma unroll
      for (int ni = 0; ni < 4; ++ni) {
        const int n = wc * 64 + ni * 16 + r16;
        bf[ni] = *(const bf16x8*)((const char*)Bs + n * 128 + ((chunk ^ (n & 7)) * 16));
      }
#pragma unroll
      for (int mi = 0; mi < 4; ++mi)
#pragma unroll
        for (int ni = 0; ni < 4; ++ni)
          acc[mi][ni] = __builtin_amdgcn_mfma_f32_16x16x32_bf16(
              af[mi], bf[ni], acc[mi][ni], 0, 0, 0);
    }
    __syncthreads();
  }

  const int colb = (nb * 2 + wc) * 32;
#pragma unroll
  for (int mi = 0; mi < 4; ++mi)
#pragma unroll
    for (int r = 0; r < 4; ++r) {
      const int m = wr * 64 + mi * 16 + g * 4 + r;
      if (m < mlim) {
#pragma unroll
        for (int ni = 0; ni < 2; ++ni) {
          float h1 = acc[mi][ni][r];
          float h3 = acc[mi][ni + 2][r];
          float y = h1 / (1.f + expf(-h1)) * h3;
          inter[(size_t)(slot0 + m) * kI + colb + ni * 16 + r16] = f2bf(y);
        }
      }
    }
}

// ========================= small kernels ====================================

__global__ __launch_bounds__(256) void router_convhs_kernel(
    const float* __restrict__ hs, const float* __restrict__ gw,
    int* __restrict__ cnt, int* __restrict__ tok_e, float* __restrict__ tok_w,
    short* __restrict__ hsb) {
  if (blockIdx.x >= kT / 4) {
    const int idx = (blockIdx.x - kT / 4) * 256 + threadIdx.x;
    const float* p = hs + (size_t)idx * 8;
    float4 a = *(const float4*)p;
    float4 b = *(const float4*)(p + 4);
    bf16x8 w;
    w[0] = f2bf(a.x); w[1] = f2bf(a.y); w[2] = f2bf(a.z); w[3] = f2bf(a.w);
    w[4] = f2bf(b.x); w[5] = f2bf(b.y); w[6] = f2bf(b.z); w[7] = f2bf(b.w);
    *(bf16x8*)(hsb + (size_t)idx * 8) = w;
    return;
  }
  const int lane = threadIdx.x & 63;
  const int wid  = threadIdx.x >> 6;
  const int t = blockIdx.x * 4 + wid;
  const float* hrow = hs + (size_t)t * kH;
  float acc[kNE];
#pragma unroll
  for (int e = 0; e < kNE; ++e) acc[e] = 0.f;
  for (int i = lane; i < kH; i += 64) {
    float x = hrow[i];
    float4 g0 = *(const float4*)(gw + (size_t)i * kNE);
    float4 g1 = *(const float4*)(gw + (size_t)i * kNE + 4);
    acc[0] += x * g0.x; acc[1] += x * g0.y; acc[2] += x * g0.z; acc[3] += x * g0.w;
    acc[4] += x * g1.x; acc[5] += x * g1.y; acc[6] += x * g1.z; acc[7] += x * g1.w;
  }
#pragma unroll
  for (int o = 32; o; o >>= 1)
#pragma unroll
    for (int e = 0; e < kNE; ++e) acc[e] += __shfl_xor(acc[e], o);
  if (lane == 0) {
    int e0 = 0;
#pragma unroll
    for (int e = 1; e < kNE; ++e) if (acc[e] > acc[e0]) e0 = e;
    int e1 = (e0 == 0) ? 1 : 0;
#pragma unroll
    for (int e = 0; e < kNE; ++e) if (e != e0 && acc[e] > acc[e1]) e1 = e;
    float d  = acc[e1] - acc[e0];
    float w0 = 1.f / (1.f + expf(d));
    float w1 = 1.f / (1.f + expf(-d));
    atomicAdd(&cnt[e0], 1);
    atomicAdd(&cnt[e1], 1);
    tok_e[t * 2] = e0; tok_e[t * 2 + 1] = e1;
    tok_w[t * 2] = w0; tok_w[t * 2 + 1] = w1;
  }
}

__global__ __launch_bounds__(256) void offsets_kernel(
    const int* __restrict__ cnt, int* __restrict__ off,
    int* __restrict__ slot_token, float* __restrict__ slot_weight) {
  if (threadIdx.x == 0) {
    int o = 0;
#pragma unroll
    for (int e = 0; e < kNE; ++e) { off[e] = o; o += (cnt[e] + 63) & ~63; }
    off[kNE] = o;
  }
  for (int i = threadIdx.x; i < kSlotPad; i += 256) {
    slot_token[i]  = -1;
    slot_weight[i] = 0.f;
  }
}

__global__ __launch_bounds__(256) void assign_kernel(
    const int* __restrict__ tok_e, const float* __restrict__ tok_w,
    const int* __restrict__ off, int* __restrict__ cursor,
    int* __restrict__ slot_token, float* __restrict__ slot_weight,
    int* __restrict__ token_slots) {
  const int t = blockIdx.x * 256 + threadIdx.x;
  if (t >= kT) return;
#pragma unroll
  for (int k = 0; k < 2; ++k) {
    int e = tok_e[t * 2 + k];
    int pos = off[e] + atomicAdd(&cursor[e], 1);
    slot_token[pos]  = t;
    slot_weight[pos] = tok_w[t * 2 + k];
    token_slots[t * 2 + k] = pos;
  }
}

// ----- tconv_v4: pipelined transpose+convert, block = 128k x 128n -----------
// MODE 0: w1/w3 -> packed w13t [E][8192][1024]; z = e + 8*sel.
// MODE 1: w2 -> w2t [E][1024][4096]; z = e. (non-ovl path only)
template <int MODE>
__global__ __launch_bounds__(256) void tconv_v4(
    const float* __restrict__ s1, const float* __restrict__ s3,
    short* __restrict__ dst0) {
  constexpr int K = MODE ? kI : kH;
  constexpr int N = MODE ? kH : kI;
  const int z = blockIdx.z;
  const int e = z & 7, sel = z >> 3;
  const float* src = (MODE ? s1 : (sel ? s3 : s1)) + (size_t)e * kH * kI;
  const int tb = blockIdx.x;
  const int nb = (tb & (N / 128 - 1)) * 128;
  const int kb = (tb / (N / 128)) * 128;
  __shared__ __align__(16) float lds[128 * 128];
  const int tid = threadIdx.x;
#pragma unroll
  for (int p = 0; p < 16; ++p) {
    const int q = p * 256 + tid;
    const int k = q >> 5;
    const int nc = (q & 31) * 4;
    gload16(src + (size_t)(kb + k) * N + nb + nc, (char*)lds + (size_t)q * 16);
  }
  const int c = tid & 127;
  const int kh2 = tid >> 7;
  const int n = nb + c;
  size_t drow;
  if (MODE == 0) drow = (size_t)e * 8192 + ((n >> 5) * 64 + sel * 32 + (n & 31));
  else           drow = (size_t)e * kH + n;
  short* dbase = dst0 + drow * K + kb;
#define CONV_SUB(S, WAITSTR)                                                  \
  do {                                                                        \
    asm volatile(WAITSTR ::: "memory");                                       \
    __builtin_amdgcn_s_barrier();                                             \
    __builtin_amdgcn_sched_barrier(0);                                        \
    _Pragma("unroll")                                                         \
    for (int i = 0; i < 2; ++i) {                                             \
      const int kc = (S) * 4 + kh2 * 2 + i;                                   \
      bf16x8 v;                                                               \
      _Pragma("unroll")                                                       \
      for (int j = 0; j < 8; ++j) v[j] = f2bf(lds[(kc * 8 + j) * 128 + c]);   \
      *(bf16x8*)(dbase + kc * 8) = v;                                         \
    }                                                                         \
  } while (0)
  CONV_SUB(0, "s_waitcnt vmcnt(12)");
  CONV_SUB(1, "s_waitcnt vmcnt(8)");
  CONV_SUB(2, "s_waitcnt vmcnt(4)");
  CONV_SUB(3, "s_waitcnt vmcnt(0)");
#undef CONV_SUB
}

// r8 combined g1 (+w2t transpose on z=8,9).
__global__ __launch_bounds__(256, 3) void g1_kernel(
    const short* __restrict__ hsb, const short* __restrict__ w13t,
    const int* __restrict__ cnt, const int* __restrict__ off,
    const int* __restrict__ slot_token, short* __restrict__ inter,
    const float* __restrict__ w2s, short* __restrict__ w2t) {
  __shared__ __align__(16) char smem[32768];
  if (blockIdx.z >= 8) {
    w2t_pair(smem, ((blockIdx.z - 8) * 16 + blockIdx.y) * 64 + blockIdx.x,
             w2s, w2t);
    return;
  }
  g1_gemm_block(smem, blockIdx.z, blockIdx.y, blockIdx.x,
                hsb, w13t, cnt, off, slot_token, inter);
}

// --------- GEMM2: slot_out = w_slot * (inter @ w2), full-K, XCD-swizzled ----
// 1024 blocks, 1D grid. Logical id (nb fastest): lid = (e*16+rb)*8+nb.
// XCD-chunked remap: lid = (bid&7)*128 + (bid>>3)  (bijective, 1024%8==0).
__global__ __launch_bounds__(256, 3) void g2_kernel(
    const short* __restrict__ inter, const short* __restrict__ w2t,
    const int* __restrict__ cnt, const int* __restrict__ off,
    const float* __restrict__ slot_weight, float* __restrict__ slot_out) {
  const int bid = blockIdx.x;
  const int lid = (bid & 7) * 128 + (bid >> 3);
  const int nb = lid & 7;
  const int rb = (lid >> 3) & 15;
  const int e  = lid >> 7;
  const int count = cnt[e];
  if (rb * 128 >= count) return;
  const int slot0 = off[e] + rb * 128;
  const int mlim = ((count + 63) & ~63) - rb * 128;

  __shared__ __align__(16) short As[128 * 64];
  __shared__ __align__(16) short Bs[128 * 64];

  const int tid = threadIdx.x;
  const int l = tid & 63, w = tid >> 6;
  const int wr = w >> 1, wc = w & 1;

  const int srow = l >> 3;
  const int sch  = (l & 7) ^ srow;
  const short* aptr[4];
  const short* bptr[4];
  unsigned sdst[4];
#pragma unroll
  for (int i = 0; i < 4; ++i) {
    const int q = w * 4 + i;
    const int row = q * 8 + srow;
    int sr = slot0 + row; if (sr >= kMaxSlots) sr = kMaxSlots - 1;
    aptr[i] = inter + (size_t)sr * kI + sch * 8;
    bptr[i] = w2t + ((size_t)e * kH + nb * 128 + row) * kI + sch * 8;
    sdst[i] = (unsigned)(q * 1024 + l * 16);
  }

  f32x4 acc[4][4];
#pragma unroll
  for (int mi = 0; mi < 4; ++mi)
#pragma unroll
    for (int ni = 0; ni < 4; ++ni)
#pragma unroll
      for (int r = 0; r < 4; ++r) acc[mi][ni][r] = 0.f;

  const int r16 = l & 15, g = l >> 4;

  for (int t = 0; t < kI / 64; ++t) {
    const int k0 = t * 64;
#pragma unroll
    for (int i = 0; i < 4; ++i) {
      gload16(aptr[i] + k0, (char*)As + sdst[i]);
      gload16(bptr[i] + k0, (char*)Bs + sdst[i]);
    }
    __syncthreads();
#pragma unroll
    for (int kk = 0; kk < 2; ++kk) {
      const int chunk = kk * 4 + g;
      bf16x8 af[4], bf[4];
#pragma unroll
      for (int mi = 0; mi < 4; ++mi) {
        const int m = wr * 64 + mi * 16 + r16;
        af[mi] = *(const bf16x8*)((const char*)As + m * 128 + ((chunk ^ (m & 7)) * 16));
      }
#pragma unroll
      for (int ni = 0; ni < 4; ++ni) {
        const int n = wc * 64 + ni * 16 + r16;
        bf[ni] = *(const bf16x8*)((const char*)Bs + n * 128 + ((chunk ^ (n & 7)) * 16));
      }
#pragma unroll
      for (int mi = 0; mi < 4; ++mi)
#pragma unroll
        for (int ni = 0; ni < 4; ++ni)
          acc[mi][ni] = __builtin_amdgcn_mfma_f32_16x16x32_bf16(
              af[mi], bf[ni], acc[mi][ni], 0, 0, 0);
    }
    __syncthreads();
  }

#pragma unroll
  for (int mi = 0; mi < 4; ++mi)
#pragma unroll
    for (int r = 0; r < 4; ++r) {
      const int m = wr * 64 + mi * 16 + g * 4 + r;
      if (m < mlim) {
        const float sw = slot_weight[slot0 + m];
        const size_t orow = (size_t)(slot0 + m) * kH;
#pragma unroll
        for (int ni = 0; ni < 4; ++ni)
          slot_out[orow + nb * 128 + wc * 64 + ni * 16 + r16] =
              sw * acc[mi][ni][r];
      }
    }
}

// ------- combine: out[t] = slot_out[s0] + slot_out[s1] ----------------------
__global__ __launch_bounds__(256) void combine2_kernel(
    const float* __restrict__ slot_out, const int* __restrict__ token_slots,
    float* __restrict__ out) {
  int idx = blockIdx.x * 256 + threadIdx.x;
  int t = idx >> 8;
  int c = (idx & 255) * 4;
  int s0 = token_slots[t * 2];
  int s1 = token_slots[t * 2 + 1];
  float4 a = *(const float4*)(slot_out + (size_t)s0 * kH + c);
  float4 b = *(const float4*)(slot_out + (size_t)s1 * kH + c);
  float4 o;
  o.x = a.x + b.x; o.y = a.y + b.y; o.z = a.z + b.z; o.w = a.w + b.w;
  *(float4*)(out + (size_t)t * kH + c) = o;
}

// ===================== fallback path (r1, in-loop convert) ==================
__global__ __launch_bounds__(256) void fb_mlp1(
    const float* __restrict__ hs,
    const float* __restrict__ w1s, const float* __restrict__ w3s,
    const int* __restrict__ cnt, const int* __restrict__ off,
    const int* __restrict__ slot_token, short* __restrict__ inter) {
  const int e = blockIdx.z;
  const int count = cnt[e];
  const int rb = blockIdx.y;
  if (rb * 64 >= count) return;
  const int slot0 = off[e] + rb * 64;
  const int nb = blockIdx.x * 128;
  __shared__ __align__(16) short As[4 * 64 * 8];
  __shared__ __align__(16) short Bs[2][4 * 128 * 8];
  const int tid  = threadIdx.x;
  const int lane = tid & 63;
  const int wid  = tid >> 6;
  const int wr = wid >> 1, wc = wid & 1;
  const int am = tid & 63, akb = tid >> 6;
  int tok = slot_token[slot0 + am];
  if (tok < 0) tok = 0;
  const float* arow = hs + (size_t)tok * kH + akb * 8;
  const int which = tid >> 7;
  const int bn0 = (tid & 31) * 4;
  const int bkb = (tid >> 5) & 3;
  const float* wbase = (which ? w3s : w1s) +
      (size_t)e * kH * kI + (size_t)(bkb * 8) * kI + nb + bn0;
  char* bdstp = (char*)&Bs[which][0];
  f32x4 acc[2][2][4];
#pragma unroll
  for (int s = 0; s < 2; ++s)
#pragma unroll
    for (int mi = 0; mi < 2; ++mi)
#pragma unroll
      for (int ni = 0; ni < 4; ++ni)
#pragma unroll
        for (int r = 0; r < 4; ++r) acc[s][mi][ni][r] = 0.f;
  const int g = lane >> 4, r16 = lane & 15;
  for (int k0 = 0; k0 < kH; k0 += 32) {
    float4 a0 = *(const float4*)(arow + k0);
    float4 a1 = *(const float4*)(arow + k0 + 4);
    bf16x8 av;
    av[0] = f2bf(a0.x); av[1] = f2bf(a0.y); av[2] = f2bf(a0.z); av[3] = f2bf(a0.w);
    av[4] = f2bf(a1.x); av[5] = f2bf(a1.y); av[6] = f2bf(a1.z); av[7] = f2bf(a1.w);
    *(bf16x8*)&As[(akb * 64 + am) * 8] = av;
    {
      const float* bp = wbase + (size_t)k0 * kI;
      float4 v[8];
#pragma unroll
      for (int j = 0; j < 8; ++j) v[j] = *(const float4*)(bp + (size_t)j * kI);
      const float* vf = (const float*)v;
#pragma unroll
      for (int i = 0; i < 4; ++i) {
        bf16x8 w;
#pragma unroll
        for (int j = 0; j < 8; ++j) w[j] = f2bf(vf[j * 4 + i]);
        int n = bn0 + i;
        unsigned ba = (unsigned)((bkb * 128 + n) * 16) ^ ((((unsigned)n >> 3) & 7u) << 4);
        *(bf16x8*)(bdstp + ba) = w;
      }
    }
    __syncthreads();
    bf16x8 af[2], bfr[2][4];
#pragma unroll
    for (int mi = 0; mi < 2; ++mi)
      af[mi] = *(const bf16x8*)&As[(g * 64 + wr * 32 + mi * 16 + r16) * 8];
#pragma unroll
    for (int s = 0; s < 2; ++s)
#pragma unroll
      for (int ni = 0; ni < 4; ++ni) {
        int n = wc * 64 + ni * 16 + r16;
        unsigned ba = (unsigned)((g * 128 + n) * 16) ^ ((((unsigned)n >> 3) & 7u) << 4);
        bfr[s][ni] = *(const bf16x8*)((char*)&Bs[s][0] + ba);
      }
#pragma unroll
    for (int s = 0; s < 2; ++s)
#pragma unroll
      for (int mi = 0; mi < 2; ++mi)
#pragma unroll
        for (int ni = 0; ni < 4; ++ni)
          acc[s][mi][ni] = __builtin_amdgcn_mfma_f32_16x16x32_bf16(
              af[mi], bfr[s][ni], acc[s][mi][ni], 0, 0, 0);
    __syncthreads();
  }
#pragma unroll
  for (int mi = 0; mi < 2; ++mi)
#pragma unroll
    for (int ni = 0; ni < 4; ++ni)
#pragma unroll
      for (int r = 0; r < 4; ++r) {
        float h1 = acc[0][mi][ni][r];
        float h3 = acc[1][mi][ni][r];
        float y = h1 / (1.f + expf(-h1)) * h3;
        int m = wr * 32 + mi * 16 + g * 4 + r;
        int n = nb + wc * 64 + ni * 16 + r16;
        inter[(size_t)(slot0 + m) * kI + n] = f2bf(y);
      }
}

__global__ __launch_bounds__(256) void fb_mlp2(
    const short* __restrict__ inter, const float* __restrict__ w2s,
    const int* __restrict__ cnt, const int* __restrict__ off,
    const float* __restrict__ slot_weight, float* __restrict__ slot_out) {
  const int e = blockIdx.z;
  const int count = cnt[e];
  const int rb = blockIdx.y;
  if (rb * 64 >= count) return;
  const int slot0 = off[e] + rb * 64;
  const int nb = blockIdx.x * 128;
  __shared__ __align__(16) short As[8 * 64 * 8];
  __shared__ __align__(16) short Bs[8 * 128 * 8];
  const int tid  = threadIdx.x;
  const int lane = tid & 63;
  const int wid  = tid >> 6;
  const int wr = wid >> 1, wc = wid & 1;
  const int am = tid & 63, akb = tid >> 6;
  const short* arow = inter + (size_t)(slot0 + am) * kI;
  const int bn0 = (tid & 31) * 4;
  const int bkb = tid >> 5;
  const float* wbase = w2s + (size_t)e * kI * kH + (size_t)(bkb * 8) * kH + nb + bn0;
  f32x4 acc[2][4];
#pragma unroll
  for (int mi = 0; mi < 2; ++mi)
#pragma unroll
    for (int ni = 0; ni < 4; ++ni)
#pragma unroll
      for (int r = 0; r < 4; ++r) acc[mi][ni][r] = 0.f;
  const int g = lane >> 4, r16 = lane & 15;
  for (int k0 = 0; k0 < kI; k0 += 64) {
    bf16x8 x0 = *(const bf16x8*)(arow + k0 + akb * 8);
    bf16x8 x1 = *(const bf16x8*)(arow + k0 + (akb + 4) * 8);
    *(bf16x8*)&As[(akb * 64 + am) * 8] = x0;
    *(bf16x8*)&As[((akb + 4) * 64 + am) * 8] = x1;
    {
      const float* bp = wbase + (size_t)k0 * kH;
      float4 v[8];
#pragma unroll
      for (int j = 0; j < 8; ++j) v[j] = *(const float4*)(bp + (size_t)j * kH);
      const float* vf = (const float*)v;
#pragma unroll
      for (int i = 0; i < 4; ++i) {
        bf16x8 w;
#pragma unroll
        for (int j = 0; j < 8; ++j) w[j] = f2bf(vf[j * 4 + i]);
        int n = bn0 + i;
        unsigned ba = (unsigned)((bkb * 128 + n) * 16) ^ ((((unsigned)n >> 3) & 7u) << 4);
        *(bf16x8*)((char*)&Bs[0] + ba) = w;
      }
    }
    __syncthreads();
#pragma unroll
    for (int kk = 0; kk < 2; ++kk) {
      bf16x8 af[2], bfr[4];
#pragma unroll
      for (int mi = 0; mi < 2; ++mi)
        af[mi] = *(const bf16x8*)&As[((kk * 4 + g) * 64 + wr * 32 + mi * 16 + r16) * 8];
#pragma unroll
      for (int ni = 0; ni < 4; ++ni) {
        int n = wc * 64 + ni * 16 + r16;
        unsigned ba = (unsigned)(((kk * 4 + g) * 128 + n) * 16) ^ ((((unsigned)n >> 3) & 7u) << 4);
        bfr[ni] = *(const bf16x8*)((char*)&Bs[0] + ba);
      }
#pragma unroll
      for (int mi = 0; mi < 2; ++mi)
#pragma unroll
        for (int ni = 0; ni < 4; ++ni)
          acc[mi][ni] = __builtin_amdgcn_mfma_f32_16x16x32_bf16(
              af[mi], bfr[ni], acc[mi][ni], 0, 0, 0);
    }
    __syncthreads();
  }
  float sw[2][4];
#pragma unroll
  for (int mi = 0; mi < 2; ++mi)
#pragma unroll
    for (int r = 0; r < 4; ++r)
      sw[mi][r] = slot_weight[slot0 + wr * 32 + mi * 16 + g * 4 + r];
#pragma unroll
  for (int mi = 0; mi < 2; ++mi)
#pragma unroll
    for (int ni = 0; ni < 4; ++ni)
#pragma unroll
      for (int r = 0; r < 4; ++r) {
        int m = wr * 32 + mi * 16 + g * 4 + r;
        int n = nb + wc * 64 + ni * 16 + r16;
        slot_out[(size_t)(slot0 + m) * kH + n] = sw[mi][r] * acc[mi][ni][r];
      }
}

// ============================== launcher ====================================
extern "C" void kernel_launch(void* const* d_in, const int* in_sizes, int n_in,
                              void* d_out, int out_size, void* d_ws, size_t ws_size,
                              hipStream_t stream) {
  (void)in_sizes; (void)n_in; (void)out_size;
  const float* hs  = (const float*)d_in[0];
  const float* gw  = (const float*)d_in[1];
  const float* w1s = (const float*)d_in[2];
  const float* w2s = (const float*)d_in[3];
  const float* w3s = (const float*)d_in[4];
  float* out = (float*)d_out;
  char* ws = (char*)d_ws;

  // shared control region
  int*   cnt         = (int*)(ws + 0);
  int*   cursor      = (int*)(ws + 64);
  int*   off         = (int*)(ws + 128);
  int*   tok_e       = (int*)(ws + 256);
  float* tok_w       = (float*)(ws + 16640);
  int*   token_slots = (int*)(ws + 33024);
  int*   slot_token  = (int*)(ws + 49408);
  float* slot_weight = (float*)(ws + 68352);

  constexpr size_t OFF_HSB     = 131072;
  constexpr size_t OFF_W13T    = OFF_HSB + (size_t)kT * kH * 2;     // 4,325,376
  constexpr size_t SZ_W13T     = (size_t)kNE * 8192 * kH * 2;       // 134,217,728
  constexpr size_t OFF_INTER   = OFF_W13T + SZ_W13T;                // 138,543,104
  constexpr size_t SZ_INTER    = (size_t)kMaxSlots * kI * 2;        // 37,748,736
  constexpr size_t NEED        = OFF_INTER + SZ_INTER;              // 176,291,840
  constexpr size_t OFF_W2T_OVL = OFF_W13T;                          // overlay (non-ovl)
  constexpr size_t OFF_SLOTOUT = OFF_W13T + (size_t)kNE * kH * kI * 2; // 71,434,240
  constexpr size_t SZ_W2T      = (size_t)kNE * kH * kI * 2;         // 67,108,864
  constexpr size_t OFF_W2T2    = NEED;
  constexpr size_t NEED2       = NEED + SZ_W2T;                     // 243,400,704

  hipMemsetAsync(ws, 0, 256, stream);

  if (ws_size >= NEED) {
    short* hsb      = (short*)(ws + OFF_HSB);
    short* w13t     = (short*)(ws + OFF_W13T);
    short* inter    = (short*)(ws + OFF_INTER);
    float* slot_out = (float*)(ws + OFF_SLOTOUT);
    const bool ovl  = (ws_size >= NEED2);
    short* w2t      = (short*)(ws + (ovl ? OFF_W2T2 : OFF_W2T_OVL));

    router_convhs_kernel<<<kT / 4 + kT * kH / 8 / 256, 256, 0, stream>>>(
        hs, gw, cnt, tok_e, tok_w, hsb);
    offsets_kernel<<<1, 256, 0, stream>>>(cnt, off, slot_token, slot_weight);
    assign_kernel<<<kT / 256, 256, 0, stream>>>(tok_e, tok_w, off, cursor,
                                                slot_token, slot_weight, token_slots);
    tconv_v4<0><<<dim3(256, 1, 16), 256, 0, stream>>>(w1s, w3s, w13t);
    if (ovl) {
      // w2 transpose rides along on z=8,9 (r8 proven schedule)
      g1_kernel<<<dim3(64, 16, 10), 256, 0, stream>>>(
          hsb, w13t, cnt, off, slot_token, inter, w2s, w2t);
    } else {
      g1_kernel<<<dim3(64, 16, 8), 256, 0, stream>>>(
          hsb, w13t, cnt, off, slot_token, inter, w2s, w2t);
      tconv_v4<1><<<dim3(256, 1, 8), 256, 0, stream>>>(w2s, nullptr, w2t);
    }
    g2_kernel<<<1024, 256, 0, stream>>>(
        inter, w2t, cnt, off, slot_weight, slot_out);
    combine2_kernel<<<(kT * kH / 4) / 256, 256, 0, stream>>>(
        slot_out, token_slots, out);
  } else {
    // fallback: r1 layout
    float* slot_out = (float*)(ws + 131072);
    short* inter    = (short*)(ws + 131072 + 18874368);
    router_convhs_kernel<<<kT / 4, 256, 0, stream>>>(
        hs, gw, cnt, tok_e, tok_w, (short*)(ws + OFF_HSB));
    offsets_kernel<<<1, 256, 0, stream>>>(cnt, off, slot_token, slot_weight);
    assign_kernel<<<kT / 256, 256, 0, stream>>>(tok_e, tok_w, off, cursor,
                                                slot_token, slot_weight, token_slots);
    fb_mlp1<<<dim3(kI / 128, kT / 64, kNE), 256, 0, stream>>>(
        hs, w1s, w3s, cnt, off, slot_token, inter);
    fb_mlp2<<<dim3(kH / 128, kT / 64, kNE), 256, 0, stream>>>(
        inter, w2s, cnt, off, slot_weight, slot_out);
    combine2_kernel<<<(kT * kH / 4) / 256, 256, 0, stream>>>(
        slot_out, token_slots, out);
  }
}

// Round 12
// 337.864 us; speedup vs baseline: 1.1475x; 1.1135x over previous
//
#include <hip/hip_runtime.h>
#include <hip/hip_bf16.h>
#include <math.h>

// MoE: 8 experts, top-2, H=1024, I=4096, T=2048. f32 in/out, bf16 MFMA inside.
// Round 12: fused-B g1 — NO weight pre-transpose pass. g1 stages w1/w3 f32
// directly: per thread 8k x 4n patch via global_load_dwordx4 (coalesced),
// v_cvt_pk_bf16_f32 convert, ds_write_b128 into swizzled Bs
// (s = chunk ^ (c&7) ^ ((c>>3)&7); read 2-way-free, write ~4-way).
// w2 transpose still rides on g1 z=8,9. g2 = r11 (XCD swizzle, full-K).
constexpr int kNE = 8;
constexpr int kH  = 1024;
constexpr int kI  = 4096;
constexpr int kT  = 2048;
constexpr int kMaxSlots = kT * 2 + kNE * 64;   // 4608
constexpr int kSlotPad  = kMaxSlots + 128;

typedef short bf16x8 __attribute__((ext_vector_type(8)));
typedef float f32x4  __attribute__((ext_vector_type(4)));

__device__ __forceinline__ short f2bf(float f) {
  union { float f; unsigned u; } v; v.f = f;
  unsigned r = v.u + 0x7fffu + ((v.u >> 16) & 1u);   // RNE
  return (short)(r >> 16);
}

__device__ __forceinline__ int cvtpk(float lo, float hi) {
  int r;
  asm("v_cvt_pk_bf16_f32 %0, %1, %2" : "=v"(r) : "v"(lo), "v"(hi));
  return r;
}

__device__ __forceinline__ void gload16(const void* g, void* lds) {
  __builtin_amdgcn_global_load_lds(
      (const __attribute__((address_space(1))) void*)g,
      (__attribute__((address_space(3))) void*)lds, 16, 0, 0);
}

// ================= shared device building blocks ============================

// w2 transpose pair (two 128k x 64n tiles, 32KB LDS). dst: w2t [E][1024][4096].
__device__ __forceinline__ void w2t_pair(
    char* smemraw, int bt, const float* __restrict__ w2s,
    short* __restrict__ w2t) {
  float* tile = (float*)smemraw;
  const int tid = threadIdx.x;
#pragma unroll 1
  for (int s = 0; s < 2; ++s) {
    const int t = bt * 2 + s;                       // 0..4095
    const int e2 = t >> 9;
    const int r = t & 511;
    const int kbT = (r >> 4) * 128;
    const int nbT = (r & 15) * 64;
    const float* src = w2s + ((size_t)e2 * kI + kbT) * kH + nbT;
    if (s) __syncthreads();                         // LDS reuse WAR
#pragma unroll
    for (int p = 0; p < 8; ++p) {
      const int q = p * 256 + tid;
      const int k = q >> 4;
      const int nc = (q & 15) * 4;
      gload16(src + (size_t)k * kH + nc, (char*)tile + q * 16);
    }
    __syncthreads();                                // drains vmcnt
    const int c = tid & 63;
    const int kw = tid >> 6;
    short* drow = w2t + ((size_t)e2 * kH + nbT + c) * kI + kbT;
#pragma unroll
    for (int i = 0; i < 4; ++i) {
      const int kc = kw * 4 + i;
      bf16x8 v;
#pragma unroll
      for (int j = 0; j < 8; ++j) v[j] = f2bf(tile[(kc * 8 + j) * 64 + c]);
      *(bf16x8*)(drow + kc * 8) = v;
    }
  }
}

// g1 fused block: 128m x 128packed, 4 waves, BK=64, 32KB LDS.
// A: hsb bf16 via gload16 (unchanged). B: w1/w3 f32 -> reg cvt -> swizzled Bs.
__device__ __forceinline__ void g1_gemm_block(
    char* smem, int e, int rb, int nb,
    const short* __restrict__ hsb,
    const float* __restrict__ w1s, const float* __restrict__ w3s,
    const int* __restrict__ cnt, const int* __restrict__ off,
    const int* __restrict__ slot_token, short* __restrict__ inter) {
  const int count = cnt[e];
  if (rb * 128 >= count) return;
  const int slot0 = off[e] + rb * 128;
  const int mlim = ((count + 63) & ~63) - rb * 128;

  short* As = (short*)smem;                         // 16KB [row][slot]
  short* Bs = (short*)(smem + 16384);               // 16KB [c][swz slot]
  const int tid = threadIdx.x;
  const int l = tid & 63, w = tid >> 6;
  const int wr = w >> 1, wc = w & 1;

  // ---- A staging map (gload16, source-side swizzle; r5-r11 verified) ----
  const int srow = l >> 3;
  const int sch  = (l & 7) ^ srow;
  const short* aptr[4];
  unsigned sdstA[4];
#pragma unroll
  for (int i = 0; i < 4; ++i) {
    const int q = w * 4 + i;
    const int row = q * 8 + srow;
    int tok = slot_token[slot0 + row]; if (tok < 0) tok = 0;
    aptr[i] = hsb + (size_t)tok * kH + sch * 8;
    sdstA[i] = (unsigned)(q * 1024 + l * 16);
  }

  // ---- B staging map: thread -> 8k x 4 packed-n patch ----
  const int np = tid & 31;            // n-patch: packed cols np*4 .. np*4+3
  const int kp = tid >> 5;            // k-chunk 0..7 (k = kp*8 .. +7)
  const int selB = (np >> 3) & 1;     // 0 = w1, 1 = w3
  const int rcol = nb * 64 + (np >> 4) * 32 + (np & 7) * 4;   // real col base
  const float* bsrc = (selB ? w3s : w1s) +
      (size_t)e * kH * kI + (size_t)(kp * 8) * kI + rcol;
  unsigned bw[4];
#pragma unroll
  for (int j = 0; j < 4; ++j) {
    const int c = np * 4 + j;
    bw[j] = (unsigned)(c * 128 + (((kp ^ (c & 7) ^ ((c >> 3) & 7)) & 7) * 16));
  }

  f32x4 acc[4][4];
#pragma unroll
  for (int mi = 0; mi < 4; ++mi)
#pragma unroll
    for (int ni = 0; ni < 4; ++ni)
#pragma unroll
      for (int r = 0; r < 4; ++r) acc[mi][ni][r] = 0.f;

  const int r16 = l & 15, g = l >> 4;

  for (int t = 0; t < kH / 64; ++t) {
    const int k0 = t * 64;
    // ---- B loads first (f32, coalesced 256B segments) ----
    float4 bv[8];
#pragma unroll
    for (int q2 = 0; q2 < 8; ++q2)
      bv[q2] = *(const float4*)(bsrc + (size_t)(k0 + q2) * kI);
    // ---- A async gloads (stay in flight past the cvt) ----
#pragma unroll
    for (int i = 0; i < 4; ++i)
      gload16(aptr[i] + k0, (char*)As + sdstA[i]);
    // ---- convert 8k x 4n patch -> 4 bf16x8 granules ----
    int4 gi[4];
#define CVT_GRAN(J, SEL)                                     \
    gi[J].x = cvtpk(bv[0].SEL, bv[1].SEL);                   \
    gi[J].y = cvtpk(bv[2].SEL, bv[3].SEL);                   \
    gi[J].z = cvtpk(bv[4].SEL, bv[5].SEL);                   \
    gi[J].w = cvtpk(bv[6].SEL, bv[7].SEL);
    CVT_GRAN(0, x) CVT_GRAN(1, y) CVT_GRAN(2, z) CVT_GRAN(3, w)
#undef CVT_GRAN
    // prev iteration's MFMA completed at loop-end barrier -> safe to write
#pragma unroll
    for (int j = 0; j < 4; ++j)
      *(int4*)((char*)Bs + bw[j]) = gi[j];
    __syncthreads();                  // drains A gloads + ds_writes
#pragma unroll
    for (int kk = 0; kk < 2; ++kk) {
      const int chunk = kk * 4 + g;
      bf16x8 af[4], bf[4];
#pragma unroll
      for (int mi = 0; mi < 4; ++mi) {
        const int m = wr * 64 + mi * 16 + r16;
        af[mi] = *(const bf16x8*)((const char*)As + m * 128 + ((chunk ^ (m & 7)) * 16));
      }
#pragma unroll
      for (int ni = 0; ni < 4; ++ni) {
        const int c = wc * 64 + ni * 16 + r16;
        bf[ni] = *(const bf16x8*)((const char*)Bs +
                   c * 128 + ((chunk ^ (c & 7) ^ ((c >> 3) & 7)) * 16));
      }
#pragma unroll
      for (int mi = 0; mi < 4; ++mi)
#pragma unroll
        for (int ni = 0; ni < 4; ++ni)
          acc[mi][ni] = __builtin_amdgcn_mfma_f32_16x16x32_bf16(
              af[mi], bf[ni], acc[mi][ni], 0, 0, 0);
    }
    __syncthreads();
  }

  const int colb = (nb * 2 + wc) * 32;
#pragma unroll
  for (int mi = 0; mi < 4; ++mi)
#pragma unroll
    for (int r = 0; r < 4; ++r) {
      const int m = wr * 64 + mi * 16 + g * 4 + r;
      if (m < mlim) {
#pragma unroll
        for (int ni = 0; ni < 2; ++ni) {
          float h1 = acc[mi][ni][r];
          float h3 = acc[mi][ni + 2][r];
          float y = h1 / (1.f + expf(-h1)) * h3;
          inter[(size_t)(slot0 + m) * kI + colb + ni * 16 + r16] = f2bf(y);
        }
      }
    }
}

// ========================= small kernels ====================================

__global__ __launch_bounds__(256) void router_convhs_kernel(
    const float* __restrict__ hs, const float* __restrict__ gw,
    int* __restrict__ cnt, int* __restrict__ tok_e, float* __restrict__ tok_w,
    short* __restrict__ hsb) {
  if (blockIdx.x >= kT / 4) {
    const int idx = (blockIdx.x - kT / 4) * 256 + threadIdx.x;
    const float* p = hs + (size_t)idx * 8;
    float4 a = *(const float4*)p;
    float4 b = *(const float4*)(p + 4);
    bf16x8 w;
    w[0] = f2bf(a.x); w[1] = f2bf(a.y); w[2] = f2bf(a.z); w[3] = f2bf(a.w);
    w[4] = f2bf(b.x); w[5] = f2bf(b.y); w[6] = f2bf(b.z); w[7] = f2bf(b.w);
    *(bf16x8*)(hsb + (size_t)idx * 8) = w;
    return;
  }
  const int lane = threadIdx.x & 63;
  const int wid  = threadIdx.x >> 6;
  const int t = blockIdx.x * 4 + wid;
  const float* hrow = hs + (size_t)t * kH;
  float acc[kNE];
#pragma unroll
  for (int e = 0; e < kNE; ++e) acc[e] = 0.f;
  for (int i = lane; i < kH; i += 64) {
    float x = hrow[i];
    float4 g0 = *(const float4*)(gw + (size_t)i * kNE);
    float4 g1 = *(const float4*)(gw + (size_t)i * kNE + 4);
    acc[0] += x * g0.x; acc[1] += x * g0.y; acc[2] += x * g0.z; acc[3] += x * g0.w;
    acc[4] += x * g1.x; acc[5] += x * g1.y; acc[6] += x * g1.z; acc[7] += x * g1.w;
  }
#pragma unroll
  for (int o = 32; o; o >>= 1)
#pragma unroll
    for (int e = 0; e < kNE; ++e) acc[e] += __shfl_xor(acc[e], o);
  if (lane == 0) {
    int e0 = 0;
#pragma unroll
    for (int e = 1; e < kNE; ++e) if (acc[e] > acc[e0]) e0 = e;
    int e1 = (e0 == 0) ? 1 : 0;
#pragma unroll
    for (int e = 0; e < kNE; ++e) if (e != e0 && acc[e] > acc[e1]) e1 = e;
    float d  = acc[e1] - acc[e0];
    float w0 = 1.f / (1.f + expf(d));
    float w1 = 1.f / (1.f + expf(-d));
    atomicAdd(&cnt[e0], 1);
    atomicAdd(&cnt[e1], 1);
    tok_e[t * 2] = e0; tok_e[t * 2 + 1] = e1;
    tok_w[t * 2] = w0; tok_w[t * 2 + 1] = w1;
  }
}

__global__ __launch_bounds__(256) void offsets_kernel(
    const int* __restrict__ cnt, int* __restrict__ off,
    int* __restrict__ slot_token, float* __restrict__ slot_weight) {
  if (threadIdx.x == 0) {
    int o = 0;
#pragma unroll
    for (int e = 0; e < kNE; ++e) { off[e] = o; o += (cnt[e] + 63) & ~63; }
    off[kNE] = o;
  }
  for (int i = threadIdx.x; i < kSlotPad; i += 256) {
    slot_token[i]  = -1;
    slot_weight[i] = 0.f;
  }
}

__global__ __launch_bounds__(256) void assign_kernel(
    const int* __restrict__ tok_e, const float* __restrict__ tok_w,
    const int* __restrict__ off, int* __restrict__ cursor,
    int* __restrict__ slot_token, float* __restrict__ slot_weight,
    int* __restrict__ token_slots) {
  const int t = blockIdx.x * 256 + threadIdx.x;
  if (t >= kT) return;
#pragma unroll
  for (int k = 0; k < 2; ++k) {
    int e = tok_e[t * 2 + k];
    int pos = off[e] + atomicAdd(&cursor[e], 1);
    slot_token[pos]  = t;
    slot_weight[pos] = tok_w[t * 2 + k];
    token_slots[t * 2 + k] = pos;
  }
}

// g1 wrapper: z<8 fused GEMM; z=8,9 w2 transpose ride-along.
__global__ __launch_bounds__(256, 3) void g1_kernel(
    const short* __restrict__ hsb,
    const float* __restrict__ w1s, const float* __restrict__ w3s,
    const int* __restrict__ cnt, const int* __restrict__ off,
    const int* __restrict__ slot_token, short* __restrict__ inter,
    const float* __restrict__ w2s, short* __restrict__ w2t) {
  __shared__ __align__(16) char smem[32768];
  if (blockIdx.z >= 8) {
    w2t_pair(smem, ((blockIdx.z - 8) * 16 + blockIdx.y) * 64 + blockIdx.x,
             w2s, w2t);
    return;
  }
  g1_gemm_block(smem, blockIdx.z, blockIdx.y, blockIdx.x,
                hsb, w1s, w3s, cnt, off, slot_token, inter);
}

// --------- GEMM2: slot_out = w_slot * (inter @ w2), full-K, XCD-swizzled ----
__global__ __launch_bounds__(256, 3) void g2_kernel(
    const short* __restrict__ inter, const short* __restrict__ w2t,
    const int* __restrict__ cnt, const int* __restrict__ off,
    const float* __restrict__ slot_weight, float* __restrict__ slot_out) {
  const int bid = blockIdx.x;
  const int lid = (bid & 7) * 128 + (bid >> 3);
  const int nb = lid & 7;
  const int rb = (lid >> 3) & 15;
  const int e  = lid >> 7;
  const int count = cnt[e];
  if (rb * 128 >= count) return;
  const int slot0 = off[e] + rb * 128;
  const int mlim = ((count + 63) & ~63) - rb * 128;

  __shared__ __align__(16) short As[128 * 64];
  __shared__ __align__(16) short Bs[128 * 64];

  const int tid = threadIdx.x;
  const int l = tid & 63, w = tid >> 6;
  const int wr = w >> 1, wc = w & 1;

  const int srow = l >> 3;
  const int sch  = (l & 7) ^ srow;
  const short* aptr[4];
  const short* bptr[4];
  unsigned sdst[4];
#pragma unroll
  for (int i = 0; i < 4; ++i) {
    const int q = w * 4 + i;
    const int row = q * 8 + srow;
    int sr = slot0 + row; if (sr >= kMaxSlots) sr = kMaxSlots - 1;
    aptr[i] = inter + (size_t)sr * kI + sch * 8;
    bptr[i] = w2t + ((size_t)e * kH + nb * 128 + row) * kI + sch * 8;
    sdst[i] = (unsigned)(q * 1024 + l * 16);
  }

  f32x4 acc[4][4];
#pragma unroll
  for (int mi = 0; mi < 4; ++mi)
#pragma unroll
    for (int ni = 0; ni < 4; ++ni)
#pragma unroll
      for (int r = 0; r < 4; ++r) acc[mi][ni][r] = 0.f;

  const int r16 = l & 15, g = l >> 4;

  for (int t = 0; t < kI / 64; ++t) {
    const int k0 = t * 64;
#pragma unroll
    for (int i = 0; i < 4; ++i) {
      gload16(aptr[i] + k0, (char*)As + sdst[i]);
      gload16(bptr[i] + k0, (char*)Bs + sdst[i]);
    }
    __syncthreads();
#pragma unroll
    for (int kk = 0; kk < 2; ++kk) {
      const int chunk = kk * 4 + g;
      bf16x8 af[4], bf[4];
#pragma unroll
      for (int mi = 0; mi < 4; ++mi) {
        const int m = wr * 64 + mi * 16 + r16;
        af[mi] = *(const bf16x8*)((const char*)As + m * 128 + ((chunk ^ (m & 7)) * 16));
      }
#pragma unroll
      for (int ni = 0; ni < 4; ++ni) {
        const int n = wc * 64 + ni * 16 + r16;
        bf[ni] = *(const bf16x8*)((const char*)Bs + n * 128 + ((chunk ^ (n & 7)) * 16));
      }
#pragma unroll
      for (int mi = 0; mi < 4; ++mi)
#pragma unroll
        for (int ni = 0; ni < 4; ++ni)
          acc[mi][ni] = __builtin_amdgcn_mfma_f32_16x16x32_bf16(
              af[mi], bf[ni], acc[mi][ni], 0, 0, 0);
    }
    __syncthreads();
  }

#pragma unroll
  for (int mi = 0; mi < 4; ++mi)
#pragma unroll
    for (int r = 0; r < 4; ++r) {
      const int m = wr * 64 + mi * 16 + g * 4 + r;
      if (m < mlim) {
        const float sw = slot_weight[slot0 + m];
        const size_t orow = (size_t)(slot0 + m) * kH;
#pragma unroll
        for (int ni = 0; ni < 4; ++ni)
          slot_out[orow + nb * 128 + wc * 64 + ni * 16 + r16] =
              sw * acc[mi][ni][r];
      }
    }
}

// ------- combine: out[t] = slot_out[s0] + slot_out[s1] ----------------------
__global__ __launch_bounds__(256) void combine2_kernel(
    const float* __restrict__ slot_out, const int* __restrict__ token_slots,
    float* __restrict__ out) {
  int idx = blockIdx.x * 256 + threadIdx.x;
  int t = idx >> 8;
  int c = (idx & 255) * 4;
  int s0 = token_slots[t * 2];
  int s1 = token_slots[t * 2 + 1];
  float4 a = *(const float4*)(slot_out + (size_t)s0 * kH + c);
  float4 b = *(const float4*)(slot_out + (size_t)s1 * kH + c);
  float4 o;
  o.x = a.x + b.x; o.y = a.y + b.y; o.z = a.z + b.z; o.w = a.w + b.w;
  *(float4*)(out + (size_t)t * kH + c) = o;
}

// ===================== fallback path (r1, in-loop convert) ==================
__global__ __launch_bounds__(256) void fb_mlp1(
    const float* __restrict__ hs,
    const float* __restrict__ w1s, const float* __restrict__ w3s,
    const int* __restrict__ cnt, const int* __restrict__ off,
    const int* __restrict__ slot_token, short* __restrict__ inter) {
  const int e = blockIdx.z;
  const int count = cnt[e];
  const int rb = blockIdx.y;
  if (rb * 64 >= count) return;
  const int slot0 = off[e] + rb * 64;
  const int nb = blockIdx.x * 128;
  __shared__ __align__(16) short As[4 * 64 * 8];
  __shared__ __align__(16) short Bs[2][4 * 128 * 8];
  const int tid  = threadIdx.x;
  const int lane = tid & 63;
  const int wid  = tid >> 6;
  const int wr = wid >> 1, wc = wid & 1;
  const int am = tid & 63, akb = tid >> 6;
  int tok = slot_token[slot0 + am];
  if (tok < 0) tok = 0;
  const float* arow = hs + (size_t)tok * kH + akb * 8;
  const int which = tid >> 7;
  const int bn0 = (tid & 31) * 4;
  const int bkb = (tid >> 5) & 3;
  const float* wbase = (which ? w3s : w1s) +
      (size_t)e * kH * kI + (size_t)(bkb * 8) * kI + nb + bn0;
  char* bdstp = (char*)&Bs[which][0];
  f32x4 acc[2][2][4];
#pragma unroll
  for (int s = 0; s < 2; ++s)
#pragma unroll
    for (int mi = 0; mi < 2; ++mi)
#pragma unroll
      for (int ni = 0; ni < 4; ++ni)
#pragma unroll
        for (int r = 0; r < 4; ++r) acc[s][mi][ni][r] = 0.f;
  const int g = lane >> 4, r16 = lane & 15;
  for (int k0 = 0; k0 < kH; k0 += 32) {
    float4 a0 = *(const float4*)(arow + k0);
    float4 a1 = *(const float4*)(arow + k0 + 4);
    bf16x8 av;
    av[0] = f2bf(a0.x); av[1] = f2bf(a0.y); av[2] = f2bf(a0.z); av[3] = f2bf(a0.w);
    av[4] = f2bf(a1.x); av[5] = f2bf(a1.y); av[6] = f2bf(a1.z); av[7] = f2bf(a1.w);
    *(bf16x8*)&As[(akb * 64 + am) * 8] = av;
    {
      const float* bp = wbase + (size_t)k0 * kI;
      float4 v[8];
#pragma unroll
      for (int j = 0; j < 8; ++j) v[j] = *(const float4*)(bp + (size_t)j * kI);
      const float* vf = (const float*)v;
#pragma unroll
      for (int i = 0; i < 4; ++i) {
        bf16x8 w;
#pragma unroll
        for (int j = 0; j < 8; ++j) w[j] = f2bf(vf[j * 4 + i]);
        int n = bn0 + i;
        unsigned ba = (unsigned)((bkb * 128 + n) * 16) ^ ((((unsigned)n >> 3) & 7u) << 4);
        *(bf16x8*)(bdstp + ba) = w;
      }
    }
    __syncthreads();
    bf16x8 af[2], bfr[2][4];
#pragma unroll
    for (int mi = 0; mi < 2; ++mi)
      af[mi] = *(const bf16x8*)&As[(g * 64 + wr * 32 + mi * 16 + r16) * 8];
#pragma unroll
    for (int s = 0; s < 2; ++s)
#pragma unroll
      for (int ni = 0; ni < 4; ++ni) {
        int n = wc * 64 + ni * 16 + r16;
        unsigned ba = (unsigned)((g * 128 + n) * 16) ^ ((((unsigned)n >> 3) & 7u) << 4);
        bfr[s][ni] = *(const bf16x8*)((char*)&Bs[s][0] + ba);
      }
#pragma unroll
    for (int s = 0; s < 2; ++s)
#pragma unroll
      for (int mi = 0; mi < 2; ++mi)
#pragma unroll
        for (int ni = 0; ni < 4; ++ni)
          acc[s][mi][ni] = __builtin_amdgcn_mfma_f32_16x16x32_bf16(
              af[mi], bfr[s][ni], acc[s][mi][ni], 0, 0, 0);
    __syncthreads();
  }
#pragma unroll
  for (int mi = 0; mi < 2; ++mi)
#pragma unroll
    for (int ni = 0; ni < 4; ++ni)
#pragma unroll
      for (int r = 0; r < 4; ++r) {
        float h1 = acc[0][mi][ni][r];
        float h3 = acc[1][mi][ni][r];
        float y = h1 / (1.f + expf(-h1)) * h3;
        int m = wr * 32 + mi * 16 + g * 4 + r;
        int n = nb + wc * 64 + ni * 16 + r16;
        inter[(size_t)(slot0 + m) * kI + n] = f2bf(y);
      }
}

__global__ __launch_bounds__(256) void fb_mlp2(
    const short* __restrict__ inter, const float* __restrict__ w2s,
    const int* __restrict__ cnt, const int* __restrict__ off,
    const float* __restrict__ slot_weight, float* __restrict__ slot_out) {
  const int e = blockIdx.z;
  const int count = cnt[e];
  const int rb = blockIdx.y;
  if (rb * 64 >= count) return;
  const int slot0 = off[e] + rb * 64;
  const int nb = blockIdx.x * 128;
  __shared__ __align__(16) short As[8 * 64 * 8];
  __shared__ __align__(16) short Bs[8 * 128 * 8];
  const int tid  = threadIdx.x;
  const int lane = tid & 63;
  const int wid  = tid >> 6;
  const int wr = wid >> 1, wc = wid & 1;
  const int am = tid & 63, akb = tid >> 6;
  const short* arow = inter + (size_t)(slot0 + am) * kI;
  const int bn0 = (tid & 31) * 4;
  const int bkb = tid >> 5;
  const float* wbase = w2s + (size_t)e * kI * kH + (size_t)(bkb * 8) * kH + nb + bn0;
  f32x4 acc[2][4];
#pragma unroll
  for (int mi = 0; mi < 2; ++mi)
#pragma unroll
    for (int ni = 0; ni < 4; ++ni)
#pragma unroll
      for (int r = 0; r < 4; ++r) acc[mi][ni][r] = 0.f;
  const int g = lane >> 4, r16 = lane & 15;
  for (int k0 = 0; k0 < kI; k0 += 64) {
    bf16x8 x0 = *(const bf16x8*)(arow + k0 + akb * 8);
    bf16x8 x1 = *(const bf16x8*)(arow + k0 + (akb + 4) * 8);
    *(bf16x8*)&As[(akb * 64 + am) * 8] = x0;
    *(bf16x8*)&As[((akb + 4) * 64 + am) * 8] = x1;
    {
      const float* bp = wbase + (size_t)k0 * kH;
      float4 v[8];
#pragma unroll
      for (int j = 0; j < 8; ++j) v[j] = *(const float4*)(bp + (size_t)j * kH);
      const float* vf = (const float*)v;
#pragma unroll
      for (int i = 0; i < 4; ++i) {
        bf16x8 w;
#pragma unroll
        for (int j = 0; j < 8; ++j) w[j] = f2bf(vf[j * 4 + i]);
        int n = bn0 + i;
        unsigned ba = (unsigned)((bkb * 128 + n) * 16) ^ ((((unsigned)n >> 3) & 7u) << 4);
        *(bf16x8*)((char*)&Bs[0] + ba) = w;
      }
    }
    __syncthreads();
#pragma unroll
    for (int kk = 0; kk < 2; ++kk) {
      bf16x8 af[2], bfr[4];
#pragma unroll
      for (int mi = 0; mi < 2; ++mi)
        af[mi] = *(const bf16x8*)&As[((kk * 4 + g) * 64 + wr * 32 + mi * 16 + r16) * 8];
#pragma unroll
      for (int ni = 0; ni < 4; ++ni) {
        int n = wc * 64 + ni * 16 + r16;
        unsigned ba = (unsigned)(((kk * 4 + g) * 128 + n) * 16) ^ ((((unsigned)n >> 3) & 7u) << 4);
        bfr[ni] = *(const bf16x8*)((char*)&Bs[0] + ba);
      }
#pragma unroll
      for (int mi = 0; mi < 2; ++mi)
#pragma unroll
        for (int ni = 0; ni < 4; ++ni)
          acc[mi][ni] = __builtin_amdgcn_mfma_f32_16x16x32_bf16(
              af[mi], bfr[ni], acc[mi][ni], 0, 0, 0);
    }
    __syncthreads();
  }
  float sw[2][4];
#pragma unroll
  for (int mi = 0; mi < 2; ++mi)
#pragma unroll
    for (int r = 0; r < 4; ++r)
      sw[mi][r] = slot_weight[slot0 + wr * 32 + mi * 16 + g * 4 + r];
#pragma unroll
  for (int mi = 0; mi < 2; ++mi)
#pragma unroll
    for (int ni = 0; ni < 4; ++ni)
#pragma unroll
      for (int r = 0; r < 4; ++r) {
        int m = wr * 32 + mi * 16 + g * 4 + r;
        int n = nb + wc * 64 + ni * 16 + r16;
        slot_out[(size_t)(slot0 + m) * kH + n] = sw[mi][r] * acc[mi][ni][r];
      }
}

// ============================== launcher ====================================
extern "C" void kernel_launch(void* const* d_in, const int* in_sizes, int n_in,
                              void* d_out, int out_size, void* d_ws, size_t ws_size,
                              hipStream_t stream) {
  (void)in_sizes; (void)n_in; (void)out_size;
  const float* hs  = (const float*)d_in[0];
  const float* gw  = (const float*)d_in[1];
  const float* w1s = (const float*)d_in[2];
  const float* w2s = (const float*)d_in[3];
  const float* w3s = (const float*)d_in[4];
  float* out = (float*)d_out;
  char* ws = (char*)d_ws;

  // shared control region
  int*   cnt         = (int*)(ws + 0);
  int*   cursor      = (int*)(ws + 64);
  int*   off         = (int*)(ws + 128);
  int*   tok_e       = (int*)(ws + 256);
  float* tok_w       = (float*)(ws + 16640);
  int*   token_slots = (int*)(ws + 33024);
  int*   slot_token  = (int*)(ws + 49408);
  float* slot_weight = (float*)(ws + 68352);

  // fused-path layout (no w13t buffer): 128 MB total
  constexpr size_t OFF_HSB     = 131072;
  constexpr size_t OFF_INTER   = OFF_HSB + (size_t)kT * kH * 2;        // 4,325,376
  constexpr size_t OFF_W2T     = OFF_INTER + (size_t)kMaxSlots * kI * 2; // 42,074,112
  constexpr size_t OFF_SLOTOUT = OFF_W2T + (size_t)kNE * kH * kI * 2;  // 109,182,976
  constexpr size_t NEED        = OFF_SLOTOUT + (size_t)kMaxSlots * kH * 4; // 128,057,344

  hipMemsetAsync(ws, 0, 256, stream);

  if (ws_size >= NEED) {
    short* hsb      = (short*)(ws + OFF_HSB);
    short* inter    = (short*)(ws + OFF_INTER);
    short* w2t      = (short*)(ws + OFF_W2T);
    float* slot_out = (float*)(ws + OFF_SLOTOUT);

    router_convhs_kernel<<<kT / 4 + kT * kH / 8 / 256, 256, 0, stream>>>(
        hs, gw, cnt, tok_e, tok_w, hsb);
    offsets_kernel<<<1, 256, 0, stream>>>(cnt, off, slot_token, slot_weight);
    assign_kernel<<<kT / 256, 256, 0, stream>>>(tok_e, tok_w, off, cursor,
                                                slot_token, slot_weight, token_slots);
    g1_kernel<<<dim3(64, 16, 10), 256, 0, stream>>>(
        hsb, w1s, w3s, cnt, off, slot_token, inter, w2s, w2t);
    g2_kernel<<<1024, 256, 0, stream>>>(
        inter, w2t, cnt, off, slot_weight, slot_out);
    combine2_kernel<<<(kT * kH / 4) / 256, 256, 0, stream>>>(
        slot_out, token_slots, out);
  } else {
    // fallback: r1 layout
    float* slot_out = (float*)(ws + 131072);
    short* inter    = (short*)(ws + 131072 + 18874368);
    router_convhs_kernel<<<kT / 4, 256, 0, stream>>>(
        hs, gw, cnt, tok_e, tok_w, (short*)(ws + OFF_HSB));
    offsets_kernel<<<1, 256, 0, stream>>>(cnt, off, slot_token, slot_weight);
    assign_kernel<<<kT / 256, 256, 0, stream>>>(tok_e, tok_w, off, cursor,
                                                slot_token, slot_weight, token_slots);
    fb_mlp1<<<dim3(kI / 128, kT / 64, kNE), 256, 0, stream>>>(
        hs, w1s, w3s, cnt, off, slot_token, inter);
    fb_mlp2<<<dim3(kH / 128, kT / 64, kNE), 256, 0, stream>>>(
        inter, w2s, cnt, off, slot_weight, slot_out);
    combine2_kernel<<<(kT * kH / 4) / 256, 256, 0, stream>>>(
        slot_out, token_slots, out);
  }
}